// Round 10
// baseline (1521.593 us; speedup 1.0000x reference)
//
#include <hip/hip_runtime.h>
#include <math.h>

#define NN 512
#define NP 20000
#define DD 128
#define NH 24
#define G3 384
#define NHD 3072  /* NH*DD */

typedef __attribute__((ext_vector_type(8))) short bf8_t;   /* 8 bf16 */
typedef __attribute__((ext_vector_type(4))) float f4_t;
typedef unsigned short ushort_t;

/* fast transcendentals */
__device__ __forceinline__ float sigf(float x){
  return __builtin_amdgcn_rcpf(1.f + __expf(-x));
}
__device__ __forceinline__ float tanh_fast(float x){
  float ax = fabsf(x);
  float e = __expf(-2.f*ax);
  float t = (1.f - e) * __builtin_amdgcn_rcpf(1.f + e);
  return copysignf(t, x);
}
__device__ __forceinline__ unsigned short f2bf(float f){
  unsigned int u = __float_as_uint(f);
  unsigned int r = (u + 0x7fffu + ((u>>16)&1u)) >> 16;
  return (unsigned short)r;
}
__device__ __forceinline__ float bf2f(unsigned short h){
  return __uint_as_float(((unsigned int)h)<<16);
}

/* ---------------- init ---------------- */
__global__ void k_init_ns(float* ns, const float* qp, const float* w1, const float* w2,
                          const float* w3, const float* qs){
  int n = blockIdx.x, c = threadIdx.x;
  float v = 0.f;
  if (c==0) v=qp[n]; else if (c==1) v=w1[n]; else if (c==2) v=w2[n]; else if (c==3) v=w3[n];
  else if (c<7) v=qs[n*3 + (c-4)];
  ns[n*DD+c]=v;
}

__global__ void k_init_ps(float* ps, const float* bw, const float* tos){
  int i = blockIdx.x*256 + threadIdx.x;
  if (i >= NP*DD) return;
  int p = i>>7, c = i&127;
  float v=0.f; if(c==0) v=bw[p]; else if(c==1) v=tos[p];
  ps[i]=v;
}

/* adjacency as bitmask */
__global__ void k_adj(unsigned int* adjb, const int* idx, const float* lc){
  int l = blockIdx.x*256+threadIdx.x; if(l>=4096) return;
  if (lc[l]!=0.f){
    int a = idx[l]; int i = a>>9, j = a&511;
    atomicOr(&adjb[i*16 + (j>>5)], 1u<<(j&31));
  }
}

__global__ void k_meta(const int* paths, const int* seqs, int* start, int* lens, int E){
  int e = blockIdx.x*256+threadIdx.x; if(e>=E) return;
  int p=paths[e], s=seqs[e];
  if (s==0) start[p]=e;
  if (e==E-1 || paths[e+1]!=p) lens[p]=s+1;
}

/* ---- length sort (counting sort, descending) ---- */
__global__ void k_lcount(const int* __restrict__ lens, int* lcnt){
  int p = blockIdx.x*256+threadIdx.x; if(p>=NP) return;
  atomicAdd(&lcnt[lens[p]],1);
}
__global__ void k_lscan(const int* __restrict__ lcnt, int* loff, int* lcur){
  if (threadIdx.x==0){
    int acc=0;
    for (int L=15; L>=0; --L){ loff[L]=acc; lcur[L]=acc; acc+=lcnt[L]; }
  }
}
__global__ void k_lfill(const int* __restrict__ lens, int* lcur, int* perm){
  int p = blockIdx.x*256+threadIdx.x; if(p>=NP) return;
  int pos = atomicAdd(&lcur[lens[p]],1);
  perm[pos]=p;
}

/* transpose+split: W [K][ncols] -> Wt hi/lo [ncols][K], K = 1<<shift */
__global__ void k_wsplit(const float* __restrict__ W, ushort_t* __restrict__ Wh,
                         ushort_t* __restrict__ Wl, int shift, int ncols, int total){
  int i = blockIdx.x*256 + threadIdx.x;
  if (i >= total) return;
  int col = i >> shift, k = i & ((1<<shift)-1);
  float v = W[(size_t)k*ncols + col];
  ushort_t h = f2bf(v);
  Wh[i] = h; Wl[i] = f2bf(v - bf2f(h));
}

/* batch split for the six G3xDD matrices */
__global__ void k_wsplit6(
    const float* S0,const float* S1,const float* S2,const float* S3,const float* S4,const float* S5,
    ushort_t* H0, ushort_t* L0, ushort_t* H1, ushort_t* L1, ushort_t* H2, ushort_t* L2,
    ushort_t* H3, ushort_t* L3, ushort_t* H4, ushort_t* L4, ushort_t* H5, ushort_t* L5){
  int i = blockIdx.x*256 + threadIdx.x;
  if (i >= 6*G3*DD) return;
  int m = i/(G3*DD), r = i - m*(G3*DD);
  const float* S = m==0?S0:m==1?S1:m==2?S2:m==3?S3:m==4?S4:S5;
  ushort_t* Hh = m==0?H0:m==1?H1:m==2?H2:m==3?H3:m==4?H4:H5;
  ushort_t* Ll = m==0?L0:m==1?L1:m==2?L2:m==3?L3:m==4?L4:L5;
  int col = r>>7, k = r&127;
  float v = S[(size_t)k*G3 + col];
  ushort_t h = f2bf(v);
  Hh[r] = h; Ll[r] = f2bf(v - bf2f(h));
}

/* bias folds: bxgF = bp + gb@Wp ; bxgB = bb + gb@Wb ; gbUn = gb@Un */
__global__ void k_gbw(const float* __restrict__ gb,
                      const float* __restrict__ Wp, const float* __restrict__ Wb,
                      const float* __restrict__ Un,
                      const float* __restrict__ bp, const float* __restrict__ bb,
                      float* bxgF, float* bxgB, float* gbUn){
  int m = blockIdx.x; int j = threadIdx.x; /* 384 threads */
  const float* W = m==0?Wp:(m==1?Wb:Un);
  float a = m==0?bp[j]:(m==1?bb[j]:0.f);
  for (int k=0;k<128;k++) a += gb[k]*W[(size_t)k*G3+j];
  (m==0?bxgF:(m==1?bxgB:gbUn))[j]=a;
}

/* ---------------- GAT: xp GEMM -> xpT (bf16 split, [col][node]) + fused es/en ---------------- */
__global__ __launch_bounds__(512) void k_xp2(const float* __restrict__ ns,
                      const ushort_t* __restrict__ gwh, const ushort_t* __restrict__ gwl,
                      const float* __restrict__ as_, const float* __restrict__ an_,
                      ushort_t* __restrict__ xpTh, ushort_t* __restrict__ xpTl,
                      float* __restrict__ es, float* __restrict__ en){
  __shared__ __align__(16) ushort_t XsH[32][136], XsL[32][136];
  __shared__ float ered[8][32][2];   /* [wave][row][es/en] partials */
  int r0 = blockIdx.x*32, c0 = blockIdx.y*256;
  int tid = threadIdx.x;
  int w = tid>>6, l = tid&63, lr = l&15, lg = l>>4;
  for (int idx=tid; idx<32*128; idx+=512){
    int pp=idx>>7, kk=idx&127;
    float v = ns[(size_t)(r0+pp)*DD+kk];
    ushort_t hi=f2bf(v); XsH[pp][kk]=hi; XsL[pp][kk]=f2bf(v-bf2f(hi));
  }
  __syncthreads();
  int col0 = c0 + w*32 + lr, col1 = col0 + 16;
  f4_t a00=(f4_t)(0.f), a01=(f4_t)(0.f), a10=(f4_t)(0.f), a11=(f4_t)(0.f);
  #pragma unroll
  for (int kt=0; kt<4; kt++){
    int kof = kt*32 + lg*8;
    const bf8_t Ah0 = *(const bf8_t*)&XsH[lr][kof];
    const bf8_t Al0 = *(const bf8_t*)&XsL[lr][kof];
    const bf8_t Ah1 = *(const bf8_t*)&XsH[16+lr][kof];
    const bf8_t Al1 = *(const bf8_t*)&XsL[16+lr][kof];
    const bf8_t B0h = *(const bf8_t*)(gwh + (size_t)col0*128 + kof);
    const bf8_t B0l = *(const bf8_t*)(gwl + (size_t)col0*128 + kof);
    const bf8_t B1h = *(const bf8_t*)(gwh + (size_t)col1*128 + kof);
    const bf8_t B1l = *(const bf8_t*)(gwl + (size_t)col1*128 + kof);
    a00 = __builtin_amdgcn_mfma_f32_16x16x32_bf16(Ah0,B0h,a00,0,0,0);
    a00 = __builtin_amdgcn_mfma_f32_16x16x32_bf16(Al0,B0h,a00,0,0,0);
    a00 = __builtin_amdgcn_mfma_f32_16x16x32_bf16(Ah0,B0l,a00,0,0,0);
    a01 = __builtin_amdgcn_mfma_f32_16x16x32_bf16(Ah0,B1h,a01,0,0,0);
    a01 = __builtin_amdgcn_mfma_f32_16x16x32_bf16(Al0,B1h,a01,0,0,0);
    a01 = __builtin_amdgcn_mfma_f32_16x16x32_bf16(Ah0,B1l,a01,0,0,0);
    a10 = __builtin_amdgcn_mfma_f32_16x16x32_bf16(Ah1,B0h,a10,0,0,0);
    a10 = __builtin_amdgcn_mfma_f32_16x16x32_bf16(Al1,B0h,a10,0,0,0);
    a10 = __builtin_amdgcn_mfma_f32_16x16x32_bf16(Ah1,B0l,a10,0,0,0);
    a11 = __builtin_amdgcn_mfma_f32_16x16x32_bf16(Ah1,B1h,a11,0,0,0);
    a11 = __builtin_amdgcn_mfma_f32_16x16x32_bf16(Al1,B1h,a11,0,0,0);
    a11 = __builtin_amdgcn_mfma_f32_16x16x32_bf16(Ah1,B1l,a11,0,0,0);
  }
  /* store transposed split-bf16: xpT[col][node]; 4 consecutive nodes packed */
  {
    ushort4 h00,l00,h01,l01,h10,l10,h11,l11;
    #pragma unroll
    for (int q=0;q<4;q++){
      float v; ushort_t hh;
      v=a00[q]; hh=f2bf(v); ((ushort_t*)&h00)[q]=hh; ((ushort_t*)&l00)[q]=f2bf(v-bf2f(hh));
      v=a01[q]; hh=f2bf(v); ((ushort_t*)&h01)[q]=hh; ((ushort_t*)&l01)[q]=f2bf(v-bf2f(hh));
      v=a10[q]; hh=f2bf(v); ((ushort_t*)&h10)[q]=hh; ((ushort_t*)&l10)[q]=f2bf(v-bf2f(hh));
      v=a11[q]; hh=f2bf(v); ((ushort_t*)&h11)[q]=hh; ((ushort_t*)&l11)[q]=f2bf(v-bf2f(hh));
    }
    size_t b0 = (size_t)col0*NN + r0 + lg*4;
    size_t b1 = (size_t)col1*NN + r0 + lg*4;
    *(ushort4*)(xpTh + b0)      = h00; *(ushort4*)(xpTl + b0)      = l00;
    *(ushort4*)(xpTh + b1)      = h01; *(ushort4*)(xpTl + b1)      = l01;
    *(ushort4*)(xpTh + b0 + 16) = h10; *(ushort4*)(xpTl + b0 + 16) = l10;
    *(ushort4*)(xpTh + b1 + 16) = h11; *(ushort4*)(xpTl + b1 + 16) = l11;
  }
  /* es/en partials: wave w covers one head hw, cols [w*32, w*32+32) */
  {
    int hw = blockIdx.y*2 + (w>>2);
    int cc0 = (w*32 + lr)&127, cc1 = (w*32 + 16 + lr)&127;
    float as0 = as_[hw*DD+cc0], as1 = as_[hw*DD+cc1];
    float an0 = an_[hw*DD+cc0], an1 = an_[hw*DD+cc1];
    #pragma unroll
    for (int q=0;q<4;q++){
      float s0 = a00[q]*as0 + a01[q]*as1;
      float n0 = a00[q]*an0 + a01[q]*an1;
      float s1 = a10[q]*as0 + a11[q]*as1;
      float n1 = a10[q]*an0 + a11[q]*an1;
      #pragma unroll
      for (int o=1;o<16;o<<=1){
        s0 += __shfl_xor(s0,o); n0 += __shfl_xor(n0,o);
        s1 += __shfl_xor(s1,o); n1 += __shfl_xor(n1,o);
      }
      if (lr==0){
        ered[w][lg*4+q][0]=s0;    ered[w][lg*4+q][1]=n0;
        ered[w][16+lg*4+q][0]=s1; ered[w][16+lg*4+q][1]=n1;
      }
    }
  }
  __syncthreads();
  if (tid < 128){
    int row = tid&31, hh = (tid>>5)&1, which = tid>>6;
    float v = ered[hh*4+0][row][which] + ered[hh*4+1][row][which]
            + ered[hh*4+2][row][which] + ered[hh*4+3][row][which];
    float* dst = which? en : es;
    dst[(size_t)(r0+row)*NH + blockIdx.y*2 + hh] = v;
  }
}

/* attn: max pass + single-exp pass (unnormalized P), MFMA PV, 1/s folded in epilogue */
__global__ __launch_bounds__(256) void k_attn2(
    const ushort_t* __restrict__ xpTh, const ushort_t* __restrict__ xpTl,
    const float* __restrict__ es, const float* __restrict__ en,
    const unsigned int* __restrict__ adjb, float* __restrict__ gout)
{
  __shared__ __align__(16) ushort_t PsH[32][520], PsL[32][520];
  __shared__ float enl[512], esl[32];
  __shared__ unsigned int am[32][16];
  __shared__ float isms[32];
  int h = blockIdx.x, i0 = blockIdx.y*32, tid = threadIdx.x;
  for (int j=tid; j<512; j+=256) enl[j] = en[(size_t)j*NH + h];
  for (int idx=tid; idx<512; idx+=256) am[idx>>4][idx&15] = adjb[(i0+(idx>>4))*16 + (idx&15)];
  if (tid<32) esl[tid] = es[(size_t)(i0+tid)*NH + h];
  __syncthreads();
  {
    int t8 = tid&7, ii = tid>>3;
    float esr = esl[ii];
    /* pass 1: max only */
    float m = -INFINITY;
    for (int j=t8; j<512; j+=8){
      float lv = esr + enl[j];
      lv = (lv>=0.f)? lv : 0.2f*lv;
      if (!((am[ii][j>>5]>>(j&31))&1u)) lv = -1000000000.0f;
      m = fmaxf(m, lv);
    }
    #pragma unroll
    for (int o=4;o>0;o>>=1) m = fmaxf(m, __shfl_xor(m,o));
    /* pass 2: single exp, store unnormalized split-bf16 P, register sum */
    float s = 0.f;
    for (int j=t8; j<512; j+=8){
      float lv = esr + enl[j];
      lv = (lv>=0.f)? lv : 0.2f*lv;
      if (!((am[ii][j>>5]>>(j&31))&1u)) lv = -1000000000.0f;
      float e = __expf(lv - m);
      s += e;
      ushort_t hi = f2bf(e);
      PsH[ii][j] = hi; PsL[ii][j] = f2bf(e - bf2f(hi));
    }
    #pragma unroll
    for (int o=4;o>0;o>>=1) s += __shfl_xor(s,o);
    if (t8==0) isms[ii] = __builtin_amdgcn_rcpf(s);
  }
  __syncthreads();
  /* PV via MFMA: P(32x512) @ xpT_h(512x128); wave wv owns cols [wv*32, wv*32+32) */
  int wv = tid>>6, ln = tid&63, lr = ln&15, lg = ln>>4;
  const ushort_t* B0hp = xpTh + ((size_t)(h*DD + wv*32 + lr))*NN;
  const ushort_t* B0lp = xpTl + ((size_t)(h*DD + wv*32 + lr))*NN;
  const ushort_t* B1hp = B0hp + (size_t)16*NN;
  const ushort_t* B1lp = B0lp + (size_t)16*NN;
  f4_t a00=(f4_t)(0.f), a01=(f4_t)(0.f), a10=(f4_t)(0.f), a11=(f4_t)(0.f);
  #pragma unroll
  for (int kt=0; kt<16; kt++){
    int kof = kt*32 + lg*8;
    const bf8_t A0h = *(const bf8_t*)&PsH[lr][kof];
    const bf8_t A0l = *(const bf8_t*)&PsL[lr][kof];
    const bf8_t A1h = *(const bf8_t*)&PsH[16+lr][kof];
    const bf8_t A1l = *(const bf8_t*)&PsL[16+lr][kof];
    const bf8_t B0h = *(const bf8_t*)(B0hp + kof);
    const bf8_t B0l = *(const bf8_t*)(B0lp + kof);
    const bf8_t B1h = *(const bf8_t*)(B1hp + kof);
    const bf8_t B1l = *(const bf8_t*)(B1lp + kof);
    a00 = __builtin_amdgcn_mfma_f32_16x16x32_bf16(A0h,B0h,a00,0,0,0);
    a00 = __builtin_amdgcn_mfma_f32_16x16x32_bf16(A0l,B0h,a00,0,0,0);
    a00 = __builtin_amdgcn_mfma_f32_16x16x32_bf16(A0h,B0l,a00,0,0,0);
    a01 = __builtin_amdgcn_mfma_f32_16x16x32_bf16(A0h,B1h,a01,0,0,0);
    a01 = __builtin_amdgcn_mfma_f32_16x16x32_bf16(A0l,B1h,a01,0,0,0);
    a01 = __builtin_amdgcn_mfma_f32_16x16x32_bf16(A0h,B1l,a01,0,0,0);
    a10 = __builtin_amdgcn_mfma_f32_16x16x32_bf16(A1h,B0h,a10,0,0,0);
    a10 = __builtin_amdgcn_mfma_f32_16x16x32_bf16(A1l,B0h,a10,0,0,0);
    a10 = __builtin_amdgcn_mfma_f32_16x16x32_bf16(A1h,B0l,a10,0,0,0);
    a11 = __builtin_amdgcn_mfma_f32_16x16x32_bf16(A1h,B1h,a11,0,0,0);
    a11 = __builtin_amdgcn_mfma_f32_16x16x32_bf16(A1l,B1h,a11,0,0,0);
    a11 = __builtin_amdgcn_mfma_f32_16x16x32_bf16(A1h,B1l,a11,0,0,0);
  }
  const float inv = 1.f/24.f;
  #pragma unroll
  for (int q=0;q<4;q++){
    int r0w = lg*4+q, r1w = 16+lg*4+q;
    float s0 = isms[r0w]*inv, s1 = isms[r1w]*inv;
    atomicAdd(&gout[(size_t)(i0+r0w)*DD + wv*32 + lr],      a00[q]*s0);
    atomicAdd(&gout[(size_t)(i0+r0w)*DD + wv*32 + 16 + lr], a01[q]*s0);
    atomicAdd(&gout[(size_t)(i0+r1w)*DD + wv*32 + lr],      a10[q]*s1);
    atomicAdd(&gout[(size_t)(i0+r1w)*DD + wv*32 + 16 + lr], a11[q]*s1);
  }
}

/* xg for both dirs via MFMA; bias vector includes gb@W fold */
__global__ __launch_bounds__(512) void k_xg3(const float* __restrict__ gout,
      const ushort_t* __restrict__ WpH, const ushort_t* __restrict__ WpL,
      const ushort_t* __restrict__ WbH, const ushort_t* __restrict__ WbL,
      const float* __restrict__ bxgF, const float* __restrict__ bxgB,
      float* __restrict__ xgF, float* __restrict__ xgB){
  __shared__ __align__(16) ushort_t XsH[32][136], XsL[32][136];
  int r0 = blockIdx.x*32;
  int mat = blockIdx.y/3, cg = blockIdx.y%3;
  const ushort_t* Wh = mat? WbH : WpH;
  const ushort_t* Wl = mat? WbL : WpL;
  const float* b0 = mat? bxgB : bxgF;
  float* out = mat? xgB : xgF;
  int tid = threadIdx.x;
  int w = tid>>6, l = tid&63, lr = l&15, lg = l>>4;
  for (int idx=tid; idx<32*128; idx+=512){
    int pp=idx>>7, kk=idx&127;
    float v = gout[(size_t)(r0+pp)*DD+kk];
    ushort_t hi=f2bf(v); XsH[pp][kk]=hi; XsL[pp][kk]=f2bf(v-bf2f(hi));
  }
  __syncthreads();
  int col = cg*128 + w*16 + lr;
  f4_t a0=(f4_t)(0.f), a1=(f4_t)(0.f);
  #pragma unroll
  for (int kt=0; kt<4; kt++){
    int kof = kt*32 + lg*8;
    const bf8_t Ah0 = *(const bf8_t*)&XsH[lr][kof];
    const bf8_t Al0 = *(const bf8_t*)&XsL[lr][kof];
    const bf8_t Ah1 = *(const bf8_t*)&XsH[16+lr][kof];
    const bf8_t Al1 = *(const bf8_t*)&XsL[16+lr][kof];
    const bf8_t Bh = *(const bf8_t*)(Wh + (size_t)col*128 + kof);
    const bf8_t Bl = *(const bf8_t*)(Wl + (size_t)col*128 + kof);
    a0 = __builtin_amdgcn_mfma_f32_16x16x32_bf16(Ah0,Bh,a0,0,0,0);
    a0 = __builtin_amdgcn_mfma_f32_16x16x32_bf16(Al0,Bh,a0,0,0,0);
    a0 = __builtin_amdgcn_mfma_f32_16x16x32_bf16(Ah0,Bl,a0,0,0,0);
    a1 = __builtin_amdgcn_mfma_f32_16x16x32_bf16(Ah1,Bh,a1,0,0,0);
    a1 = __builtin_amdgcn_mfma_f32_16x16x32_bf16(Al1,Bh,a1,0,0,0);
    a1 = __builtin_amdgcn_mfma_f32_16x16x32_bf16(Ah1,Bl,a1,0,0,0);
  }
  float bb0 = b0[col];
  #pragma unroll
  for (int q=0;q<4;q++){
    out[(size_t)(r0+lg*4+q)*G3 + col]    = a0[q] + bb0;
    out[(size_t)(r0+16+lg*4+q)*G3 + col] = a1[q] + bb0;
  }
}

/* ---------------- fused bidirectional path GRU (split-bf16 MFMA, 32 paths) ----------------
   __launch_bounds__(512,6): target <=85 VGPR for 3 blocks/CU (occupancy experiment) */
__global__ __launch_bounds__(512, 6) void k_gru2(
    const float* __restrict__ ps_in, float* __restrict__ ps_out,
    const float* __restrict__ xgF, const float* __restrict__ xgB,
    const ushort_t* __restrict__ UthF, const ushort_t* __restrict__ UtlF,
    const ushort_t* __restrict__ UthB, const ushort_t* __restrict__ UtlB,
    const float* __restrict__ b1F, const float* __restrict__ b1B,
    const int* __restrict__ start, const int* __restrict__ lens,
    const int* __restrict__ nodes, const int* __restrict__ perm,
    float* __restrict__ m2)
{
  __shared__ __align__(16) ushort_t HsH[2][32][136];
  __shared__ __align__(16) ushort_t HsL[2][32][136];
  __shared__ int Ls[32], Ss[32], Pid[32];
  __shared__ int nid_l[32][8];

  int dir = blockIdx.x & 1, pblk = blockIdx.x >> 1;
  const bool rev = (dir==1);
  const float* xg = rev ? xgB : xgF;
  const ushort_t* Uth = rev ? UthB : UthF;
  const ushort_t* Utl = rev ? UtlB : UtlF;
  const float* b1 = rev ? b1B : b1F;
  float* psn = rev ? (float*)0 : ps_out;

  int pb = pblk*32;
  int tid = threadIdx.x;
  int w = tid>>6, l = tid&63;
  int lr = l&15, lg = l>>4;
  int c = w*16 + lr;

  if (tid<32){ int pid = perm[pb+tid]; Pid[tid]=pid; Ls[tid]=lens[pid]; Ss[tid]=start[pid]; }
  __syncthreads();
  for (int idx=tid; idx<32*128; idx+=512){
    int pp=idx>>7, kk=idx&127;
    float v = ps_in[(size_t)Pid[pp]*DD+kk];
    ushort_t hi = f2bf(v);
    HsH[0][pp][kk]=hi; HsL[0][pp][kk]=f2bf(v - bf2f(hi));
  }
  if (tid<256){
    int p=tid>>3, s=tid&7; int L=Ls[p];
    int nid = 0;
    if (s<L){ int pos = rev ? (L-1-s) : s; nid = nodes[Ss[p]+pos]; }
    nid_l[p][s]=nid;
  }
  __syncthreads();

  int Lmax = Ls[0];
  int Lv[8];
  #pragma unroll
  for (int i=0;i<8;i++){ int p=(i>>2)*16 + lg*4 + (i&3); Lv[i]=Ls[p]; }
  float b1z = b1[c], b1r = b1[128+c], b1h = b1[256+c];

  int cur = 0;
  for (int s=0;s<Lmax;s++){
    int nxt = cur^1;
    bool act[8]; int niv[8]; float xzv[8], xrv[8], xhv[8];
    #pragma unroll
    for (int i=0;i<8;i++){
      int p=(i>>2)*16 + lg*4 + (i&3);
      act[i] = (s < Lv[i]);
      int nid = nid_l[p][s];
      niv[i] = nid;
      const float* xr = xg + (size_t)nid*G3;
      xzv[i]=xr[c]; xrv[i]=xr[128+c]; xhv[i]=xr[256+c];
    }
    f4_t accz0=(f4_t)(0.f), accz1=(f4_t)(0.f);
    f4_t accr0=(f4_t)(0.f), accr1=(f4_t)(0.f);
    f4_t acch0=(f4_t)(0.f), acch1=(f4_t)(0.f);
    #pragma unroll
    for (int kt=0; kt<4; kt++){
      int kof = kt*32 + lg*8;
      const bf8_t Ahi0 = *(const bf8_t*)&HsH[cur][lr][kof];
      const bf8_t Alo0 = *(const bf8_t*)&HsL[cur][lr][kof];
      const bf8_t Ahi1 = *(const bf8_t*)&HsH[cur][16+lr][kof];
      const bf8_t Alo1 = *(const bf8_t*)&HsL[cur][16+lr][kof];
      const bf8_t Bhz = *(const bf8_t*)(Uth + ((size_t)(      c))*128 + kof);
      const bf8_t Blz = *(const bf8_t*)(Utl + ((size_t)(      c))*128 + kof);
      const bf8_t Bhr = *(const bf8_t*)(Uth + ((size_t)(128 + c))*128 + kof);
      const bf8_t Blr = *(const bf8_t*)(Utl + ((size_t)(128 + c))*128 + kof);
      const bf8_t Bhh = *(const bf8_t*)(Uth + ((size_t)(256 + c))*128 + kof);
      const bf8_t Blh = *(const bf8_t*)(Utl + ((size_t)(256 + c))*128 + kof);
      accz0 = __builtin_amdgcn_mfma_f32_16x16x32_bf16(Ahi0, Bhz, accz0, 0,0,0);
      accz0 = __builtin_amdgcn_mfma_f32_16x16x32_bf16(Alo0, Bhz, accz0, 0,0,0);
      accz0 = __builtin_amdgcn_mfma_f32_16x16x32_bf16(Ahi0, Blz, accz0, 0,0,0);
      accz1 = __builtin_amdgcn_mfma_f32_16x16x32_bf16(Ahi1, Bhz, accz1, 0,0,0);
      accz1 = __builtin_amdgcn_mfma_f32_16x16x32_bf16(Alo1, Bhz, accz1, 0,0,0);
      accz1 = __builtin_amdgcn_mfma_f32_16x16x32_bf16(Ahi1, Blz, accz1, 0,0,0);
      accr0 = __builtin_amdgcn_mfma_f32_16x16x32_bf16(Ahi0, Bhr, accr0, 0,0,0);
      accr0 = __builtin_amdgcn_mfma_f32_16x16x32_bf16(Alo0, Bhr, accr0, 0,0,0);
      accr0 = __builtin_amdgcn_mfma_f32_16x16x32_bf16(Ahi0, Blr, accr0, 0,0,0);
      accr1 = __builtin_amdgcn_mfma_f32_16x16x32_bf16(Ahi1, Bhr, accr1, 0,0,0);
      accr1 = __builtin_amdgcn_mfma_f32_16x16x32_bf16(Alo1, Bhr, accr1, 0,0,0);
      accr1 = __builtin_amdgcn_mfma_f32_16x16x32_bf16(Ahi1, Blr, accr1, 0,0,0);
      acch0 = __builtin_amdgcn_mfma_f32_16x16x32_bf16(Ahi0, Bhh, acch0, 0,0,0);
      acch0 = __builtin_amdgcn_mfma_f32_16x16x32_bf16(Alo0, Bhh, acch0, 0,0,0);
      acch0 = __builtin_amdgcn_mfma_f32_16x16x32_bf16(Ahi0, Blh, acch0, 0,0,0);
      acch1 = __builtin_amdgcn_mfma_f32_16x16x32_bf16(Ahi1, Bhh, acch1, 0,0,0);
      acch1 = __builtin_amdgcn_mfma_f32_16x16x32_bf16(Alo1, Bhh, acch1, 0,0,0);
      acch1 = __builtin_amdgcn_mfma_f32_16x16x32_bf16(Ahi1, Blh, acch1, 0,0,0);
    }
#define EPI(i, mt, qq, AZ, AR, AH) { \
    int p = (mt)*16 + lg*4 + (qq); \
    if (act[i]) { \
      float hold = bf2f(HsH[cur][p][c]) + bf2f(HsL[cur][p][c]); \
      float z = sigf(xzv[i] + (AZ) + b1z); \
      float r = sigf(xrv[i] + (AR) + b1r); \
      float hc = tanh_fast(xhv[i] + r*((AH) + b1h)); \
      float hn = z*hold + (1.f-z)*hc; \
      ushort_t hi2 = f2bf(hn); \
      HsH[nxt][p][c]=hi2; HsL[nxt][p][c]=f2bf(hn - bf2f(hi2)); \
      atomicAdd(&m2[(size_t)niv[i]*DD + c], hn); \
    } else { \
      HsH[nxt][p][c]=HsH[cur][p][c]; HsL[nxt][p][c]=HsL[cur][p][c]; \
    } }
    EPI(0,0,0, accz0.x, accr0.x, acch0.x)
    EPI(1,0,1, accz0.y, accr0.y, acch0.y)
    EPI(2,0,2, accz0.z, accr0.z, acch0.z)
    EPI(3,0,3, accz0.w, accr0.w, acch0.w)
    EPI(4,1,0, accz1.x, accr1.x, acch1.x)
    EPI(5,1,1, accz1.y, accr1.y, acch1.y)
    EPI(6,1,2, accz1.z, accr1.z, acch1.z)
    EPI(7,1,3, accz1.w, accr1.w, acch1.w)
#undef EPI
    __syncthreads();
    cur = nxt;
  }
  if (psn){
    for (int idx=tid; idx<32*128; idx+=512){
      int pp=idx>>7, kk=idx&127;
      psn[(size_t)Pid[pp]*DD+kk] = bf2f(HsH[cur][pp][kk]) + bf2f(HsL[cur][pp][kk]);
    }
  }
}

/* ---------------- node GRU via MFMA (bias folds) ---------------- */
__global__ __launch_bounds__(512) void k_ngru3(
    const float* __restrict__ m2, const float* __restrict__ gout,
    const ushort_t* __restrict__ WnH, const ushort_t* __restrict__ WnL,
    const ushort_t* __restrict__ UnH, const ushort_t* __restrict__ UnL,
    const float* __restrict__ bn, const float* __restrict__ gb,
    const float* __restrict__ gbUn, float* __restrict__ ns)
{
  __shared__ __align__(16) ushort_t MsH[32][136], MsL[32][136];
  __shared__ __align__(16) ushort_t GsH[32][136], GsL[32][136];
  int r0 = blockIdx.x*32;
  int tid = threadIdx.x;
  int w = tid>>6, l = tid&63, lr = l&15, lg = l>>4;
  for (int idx=tid; idx<32*128; idx+=512){
    int pp=idx>>7, kk=idx&127;
    float vm = m2[(size_t)(r0+pp)*DD+kk];
    float vg = gout[(size_t)(r0+pp)*DD+kk];
    ushort_t hm=f2bf(vm); MsH[pp][kk]=hm; MsL[pp][kk]=f2bf(vm-bf2f(hm));
    ushort_t hg=f2bf(vg); GsH[pp][kk]=hg; GsL[pp][kk]=f2bf(vg-bf2f(hg));
  }
  __syncthreads();
  int c = w*16 + lr;
  f4_t xz0=(f4_t)(0.f), xr0=(f4_t)(0.f), xh0=(f4_t)(0.f);
  f4_t xz1=(f4_t)(0.f), xr1=(f4_t)(0.f), xh1=(f4_t)(0.f);
  f4_t hz0=(f4_t)(0.f), hr0=(f4_t)(0.f), hh0=(f4_t)(0.f);
  f4_t hz1=(f4_t)(0.f), hr1=(f4_t)(0.f), hh1=(f4_t)(0.f);
  #pragma unroll
  for (int kt=0; kt<4; kt++){
    int kof = kt*32 + lg*8;
    const bf8_t MA0h = *(const bf8_t*)&MsH[lr][kof];
    const bf8_t MA0l = *(const bf8_t*)&MsL[lr][kof];
    const bf8_t MA1h = *(const bf8_t*)&MsH[16+lr][kof];
    const bf8_t MA1l = *(const bf8_t*)&MsL[16+lr][kof];
    const bf8_t GA0h = *(const bf8_t*)&GsH[lr][kof];
    const bf8_t GA0l = *(const bf8_t*)&GsL[lr][kof];
    const bf8_t GA1h = *(const bf8_t*)&GsH[16+lr][kof];
    const bf8_t GA1l = *(const bf8_t*)&GsL[16+lr][kof];
    const bf8_t Wzh = *(const bf8_t*)(WnH + ((size_t)(      c))*128 + kof);
    const bf8_t Wzl = *(const bf8_t*)(WnL + ((size_t)(      c))*128 + kof);
    const bf8_t Wrh = *(const bf8_t*)(WnH + ((size_t)(128 + c))*128 + kof);
    const bf8_t Wrl = *(const bf8_t*)(WnL + ((size_t)(128 + c))*128 + kof);
    const bf8_t Whh = *(const bf8_t*)(WnH + ((size_t)(256 + c))*128 + kof);
    const bf8_t Whl = *(const bf8_t*)(WnL + ((size_t)(256 + c))*128 + kof);
    const bf8_t Uzh = *(const bf8_t*)(UnH + ((size_t)(      c))*128 + kof);
    const bf8_t Uzl = *(const bf8_t*)(UnL + ((size_t)(      c))*128 + kof);
    const bf8_t Urh = *(const bf8_t*)(UnH + ((size_t)(128 + c))*128 + kof);
    const bf8_t Url = *(const bf8_t*)(UnL + ((size_t)(128 + c))*128 + kof);
    const bf8_t Uhh = *(const bf8_t*)(UnH + ((size_t)(256 + c))*128 + kof);
    const bf8_t Uhl = *(const bf8_t*)(UnL + ((size_t)(256 + c))*128 + kof);
    xz0 = __builtin_amdgcn_mfma_f32_16x16x32_bf16(MA0h,Wzh,xz0,0,0,0);
    xz0 = __builtin_amdgcn_mfma_f32_16x16x32_bf16(MA0l,Wzh,xz0,0,0,0);
    xz0 = __builtin_amdgcn_mfma_f32_16x16x32_bf16(MA0h,Wzl,xz0,0,0,0);
    xz1 = __builtin_amdgcn_mfma_f32_16x16x32_bf16(MA1h,Wzh,xz1,0,0,0);
    xz1 = __builtin_amdgcn_mfma_f32_16x16x32_bf16(MA1l,Wzh,xz1,0,0,0);
    xz1 = __builtin_amdgcn_mfma_f32_16x16x32_bf16(MA1h,Wzl,xz1,0,0,0);
    xr0 = __builtin_amdgcn_mfma_f32_16x16x32_bf16(MA0h,Wrh,xr0,0,0,0);
    xr0 = __builtin_amdgcn_mfma_f32_16x16x32_bf16(MA0l,Wrh,xr0,0,0,0);
    xr0 = __builtin_amdgcn_mfma_f32_16x16x32_bf16(MA0h,Wrl,xr0,0,0,0);
    xr1 = __builtin_amdgcn_mfma_f32_16x16x32_bf16(MA1h,Wrh,xr1,0,0,0);
    xr1 = __builtin_amdgcn_mfma_f32_16x16x32_bf16(MA1l,Wrh,xr1,0,0,0);
    xr1 = __builtin_amdgcn_mfma_f32_16x16x32_bf16(MA1h,Wrl,xr1,0,0,0);
    xh0 = __builtin_amdgcn_mfma_f32_16x16x32_bf16(MA0h,Whh,xh0,0,0,0);
    xh0 = __builtin_amdgcn_mfma_f32_16x16x32_bf16(MA0l,Whh,xh0,0,0,0);
    xh0 = __builtin_amdgcn_mfma_f32_16x16x32_bf16(MA0h,Whl,xh0,0,0,0);
    xh1 = __builtin_amdgcn_mfma_f32_16x16x32_bf16(MA1h,Whh,xh1,0,0,0);
    xh1 = __builtin_amdgcn_mfma_f32_16x16x32_bf16(MA1l,Whh,xh1,0,0,0);
    xh1 = __builtin_amdgcn_mfma_f32_16x16x32_bf16(MA1h,Whl,xh1,0,0,0);
    hz0 = __builtin_amdgcn_mfma_f32_16x16x32_bf16(GA0h,Uzh,hz0,0,0,0);
    hz0 = __builtin_amdgcn_mfma_f32_16x16x32_bf16(GA0l,Uzh,hz0,0,0,0);
    hz0 = __builtin_amdgcn_mfma_f32_16x16x32_bf16(GA0h,Uzl,hz0,0,0,0);
    hz1 = __builtin_amdgcn_mfma_f32_16x16x32_bf16(GA1h,Uzh,hz1,0,0,0);
    hz1 = __builtin_amdgcn_mfma_f32_16x16x32_bf16(GA1l,Uzh,hz1,0,0,0);
    hz1 = __builtin_amdgcn_mfma_f32_16x16x32_bf16(GA1h,Uzl,hz1,0,0,0);
    hr0 = __builtin_amdgcn_mfma_f32_16x16x32_bf16(GA0h,Urh,hr0,0,0,0);
    hr0 = __builtin_amdgcn_mfma_f32_16x16x32_bf16(GA0l,Urh,hr0,0,0,0);
    hr0 = __builtin_amdgcn_mfma_f32_16x16x32_bf16(GA0h,Url,hr0,0,0,0);
    hr1 = __builtin_amdgcn_mfma_f32_16x16x32_bf16(GA1h,Urh,hr1,0,0,0);
    hr1 = __builtin_amdgcn_mfma_f32_16x16x32_bf16(GA1l,Urh,hr1,0,0,0);
    hr1 = __builtin_amdgcn_mfma_f32_16x16x32_bf16(GA1h,Url,hr1,0,0,0);
    hh0 = __builtin_amdgcn_mfma_f32_16x16x32_bf16(GA0h,Uhh,hh0,0,0,0);
    hh0 = __builtin_amdgcn_mfma_f32_16x16x32_bf16(GA0l,Uhh,hh0,0,0,0);
    hh0 = __builtin_amdgcn_mfma_f32_16x16x32_bf16(GA0h,Uhl,hh0,0,0,0);
    hh1 = __builtin_amdgcn_mfma_f32_16x16x32_bf16(GA1h,Uhh,hh1,0,0,0);
    hh1 = __builtin_amdgcn_mfma_f32_16x16x32_bf16(GA1l,Uhh,hh1,0,0,0);
    hh1 = __builtin_amdgcn_mfma_f32_16x16x32_bf16(GA1h,Uhl,hh1,0,0,0);
  }
  float bz = bn[c] + bn[G3+c] + gbUn[c];
  float br = bn[128+c] + bn[G3+128+c] + gbUn[128+c];
  float bxh = bn[256+c], bhh = bn[G3+256+c] + gbUn[256+c];
  float gbc = gb[c];
  #pragma unroll
  for (int q=0;q<4;q++){
    {
      int n = lg*4+q;
      float hval = bf2f(GsH[n][c]) + bf2f(GsL[n][c]) + gbc;
      float z = sigf(xz0[q] + hz0[q] + bz);
      float r = sigf(xr0[q] + hr0[q] + br);
      float hc = tanh_fast(xh0[q] + bxh + r*(hh0[q] + bhh));
      ns[(size_t)(r0+n)*DD + c] = z*hval + (1.f-z)*hc;
    }
    {
      int n = 16+lg*4+q;
      float hval = bf2f(GsH[n][c]) + bf2f(GsL[n][c]) + gbc;
      float z = sigf(xz1[q] + hz1[q] + bz);
      float r = sigf(xr1[q] + hr1[q] + br);
      float hc = tanh_fast(xh1[q] + bxh + r*(hh1[q] + bhh));
      ns[(size_t)(r0+n)*DD + c] = z*hval + (1.f-z)*hc;
    }
  }
}

/* ---------------- MFMA readout ---------------- */
__global__ __launch_bounds__(512) void k_read2(
    const float* __restrict__ ps,
    const ushort_t* __restrict__ r1h, const ushort_t* __restrict__ r1l,
    const ushort_t* __restrict__ r2h, const ushort_t* __restrict__ r2l,
    const float* __restrict__ rb1, const float* __restrict__ rb2,
    const float* __restrict__ rW3, const float* __restrict__ rb3,
    float* __restrict__ out)
{
  __shared__ __align__(16) ushort_t XsH[32][136], XsL[32][136];
  __shared__ __align__(16) char buf[32*264*2*2];
  ushort_t (*H1H)[264] = (ushort_t(*)[264])buf;
  ushort_t (*H1L)[264] = (ushort_t(*)[264])(buf + 32*264*2);
  float (*H2)[257] = (float(*)[257])buf;
  int pb = blockIdx.x*32, tid = threadIdx.x;
  int w = tid>>6, l = tid&63, lr = l&15, lg = l>>4;
  for (int idx=tid; idx<32*128; idx+=512){
    int pp=idx>>7, kk=idx&127;
    float v = ps[(size_t)(pb+pp)*DD+kk];
    ushort_t hi=f2bf(v); XsH[pp][kk]=hi; XsL[pp][kk]=f2bf(v-bf2f(hi));
  }
  __syncthreads();
  int col0 = w*32 + lr, col1 = col0 + 16;
  f4_t a00=(f4_t)(0.f), a01=(f4_t)(0.f), a10=(f4_t)(0.f), a11=(f4_t)(0.f);
  #pragma unroll
  for (int kt=0; kt<4; kt++){
    int kof = kt*32 + lg*8;
    const bf8_t Ah0 = *(const bf8_t*)&XsH[lr][kof];
    const bf8_t Al0 = *(const bf8_t*)&XsL[lr][kof];
    const bf8_t Ah1 = *(const bf8_t*)&XsH[16+lr][kof];
    const bf8_t Al1 = *(const bf8_t*)&XsL[16+lr][kof];
    const bf8_t B0h = *(const bf8_t*)(r1h + (size_t)col0*128 + kof);
    const bf8_t B0l = *(const bf8_t*)(r1l + (size_t)col0*128 + kof);
    const bf8_t B1h = *(const bf8_t*)(r1h + (size_t)col1*128 + kof);
    const bf8_t B1l = *(const bf8_t*)(r1l + (size_t)col1*128 + kof);
    a00 = __builtin_amdgcn_mfma_f32_16x16x32_bf16(Ah0,B0h,a00,0,0,0);
    a00 = __builtin_amdgcn_mfma_f32_16x16x32_bf16(Al0,B0h,a00,0,0,0);
    a00 = __builtin_amdgcn_mfma_f32_16x16x32_bf16(Ah0,B0l,a00,0,0,0);
    a01 = __builtin_amdgcn_mfma_f32_16x16x32_bf16(Ah0,B1h,a01,0,0,0);
    a01 = __builtin_amdgcn_mfma_f32_16x16x32_bf16(Al0,B1h,a01,0,0,0);
    a01 = __builtin_amdgcn_mfma_f32_16x16x32_bf16(Ah0,B1l,a01,0,0,0);
    a10 = __builtin_amdgcn_mfma_f32_16x16x32_bf16(Ah1,B0h,a10,0,0,0);
    a10 = __builtin_amdgcn_mfma_f32_16x16x32_bf16(Al1,B0h,a10,0,0,0);
    a10 = __builtin_amdgcn_mfma_f32_16x16x32_bf16(Ah1,B0l,a10,0,0,0);
    a11 = __builtin_amdgcn_mfma_f32_16x16x32_bf16(Ah1,B1h,a11,0,0,0);
    a11 = __builtin_amdgcn_mfma_f32_16x16x32_bf16(Al1,B1h,a11,0,0,0);
    a11 = __builtin_amdgcn_mfma_f32_16x16x32_bf16(Ah1,B1l,a11,0,0,0);
  }
  float rb1c0 = rb1[col0], rb1c1 = rb1[col1];
  #pragma unroll
  for (int q=0;q<4;q++){
    int row0 = lg*4+q, row1 = 16+lg*4+q;
    float v00 = a00[q]+rb1c0, v01 = a01[q]+rb1c1, v10 = a10[q]+rb1c0, v11 = a11[q]+rb1c1;
    v00 = 1.0507009873554805f * (v00>0.f ? v00 : 1.6732632423543772f*(__expf(v00)-1.f));
    v01 = 1.0507009873554805f * (v01>0.f ? v01 : 1.6732632423543772f*(__expf(v01)-1.f));
    v10 = 1.0507009873554805f * (v10>0.f ? v10 : 1.6732632423543772f*(__expf(v10)-1.f));
    v11 = 1.0507009873554805f * (v11>0.f ? v11 : 1.6732632423543772f*(__expf(v11)-1.f));
    ushort_t h;
    h=f2bf(v00); H1H[row0][col0]=h; H1L[row0][col0]=f2bf(v00-bf2f(h));
    h=f2bf(v01); H1H[row0][col1]=h; H1L[row0][col1]=f2bf(v01-bf2f(h));
    h=f2bf(v10); H1H[row1][col0]=h; H1L[row1][col0]=f2bf(v10-bf2f(h));
    h=f2bf(v11); H1H[row1][col1]=h; H1L[row1][col1]=f2bf(v11-bf2f(h));
  }
  __syncthreads();
  f4_t c00=(f4_t)(0.f), c01=(f4_t)(0.f), c10=(f4_t)(0.f), c11=(f4_t)(0.f);
  #pragma unroll
  for (int kt=0; kt<8; kt++){
    int kof = kt*32 + lg*8;
    const bf8_t Ah0 = *(const bf8_t*)&H1H[lr][kof];
    const bf8_t Al0 = *(const bf8_t*)&H1L[lr][kof];
    const bf8_t Ah1 = *(const bf8_t*)&H1H[16+lr][kof];
    const bf8_t Al1 = *(const bf8_t*)&H1L[16+lr][kof];
    const bf8_t B0h = *(const bf8_t*)(r2h + (size_t)col0*256 + kof);
    const bf8_t B0l = *(const bf8_t*)(r2l + (size_t)col0*256 + kof);
    const bf8_t B1h = *(const bf8_t*)(r2h + (size_t)col1*256 + kof);
    const bf8_t B1l = *(const bf8_t*)(r2l + (size_t)col1*256 + kof);
    c00 = __builtin_amdgcn_mfma_f32_16x16x32_bf16(Ah0,B0h,c00,0,0,0);
    c00 = __builtin_amdgcn_mfma_f32_16x16x32_bf16(Al0,B0h,c00,0,0,0);
    c00 = __builtin_amdgcn_mfma_f32_16x16x32_bf16(Ah0,B0l,c00,0,0,0);
    c01 = __builtin_amdgcn_mfma_f32_16x16x32_bf16(Ah0,B1h,c01,0,0,0);
    c01 = __builtin_amdgcn_mfma_f32_16x16x32_bf16(Al0,B1h,c01,0,0,0);
    c01 = __builtin_amdgcn_mfma_f32_16x16x32_bf16(Ah0,B1l,c01,0,0,0);
    c10 = __builtin_amdgcn_mfma_f32_16x16x32_bf16(Ah1,B0h,c10,0,0,0);
    c10 = __builtin_amdgcn_mfma_f32_16x16x32_bf16(Al1,B0h,c10,0,0,0);
    c10 = __builtin_amdgcn_mfma_f32_16x16x32_bf16(Ah1,B0l,c10,0,0,0);
    c11 = __builtin_amdgcn_mfma_f32_16x16x32_bf16(Ah1,B1h,c11,0,0,0);
    c11 = __builtin_amdgcn_mfma_f32_16x16x32_bf16(Al1,B1h,c11,0,0,0);
    c11 = __builtin_amdgcn_mfma_f32_16x16x32_bf16(Ah1,B1l,c11,0,0,0);
  }
  __syncthreads();
  float rb2c0 = rb2[col0], rb2c1 = rb2[col1];
  #pragma unroll
  for (int q=0;q<4;q++){
    int row0 = lg*4+q, row1 = 16+lg*4+q;
    H2[row0][col0] = fmaxf(c00[q]+rb2c0, 0.f);
    H2[row0][col1] = fmaxf(c01[q]+rb2c1, 0.f);
    H2[row1][col0] = fmaxf(c10[q]+rb2c0, 0.f);
    H2[row1][col1] = fmaxf(c11[q]+rb2c1, 0.f);
  }
  __syncthreads();
  int r = tid>>4, j0 = tid&15;
  float s = 0.f;
  for (int j=j0; j<256; j+=16) s += H2[r][j]*rW3[j];
  for (int o=8;o>0;o>>=1) s += __shfl_xor(s,o);
  if (j0==0) out[pb+r] = s + rb3[0];
}

/* ---------------- host ---------------- */
extern "C" void kernel_launch(void* const* d_in, const int* in_sizes, int n_in,
                              void* d_out, int out_size, void* d_ws, size_t ws_size,
                              hipStream_t stream)
{
  const float* ToS   = (const float*)d_in[0];
  const float* bw    = (const float*)d_in[1];
  const float* qpol  = (const float*)d_in[2];
  const float* w1    = (const float*)d_in[3];
  const float* w2    = (const float*)d_in[4];
  const float* w3    = (const float*)d_in[5];
  const float* qs    = (const float*)d_in[6];
  const float* lc    = (const float*)d_in[7];
  const float* gat_W = (const float*)d_in[8];
  const float* gat_as= (const float*)d_in[9];
  const float* gat_an= (const float*)d_in[10];
  const float* gat_b = (const float*)d_in[11];
  const float* Wp    = (const float*)d_in[12];
  const float* Up    = (const float*)d_in[13];
  const float* bp    = (const float*)d_in[14];
  const float* Wb    = (const float*)d_in[15];
  const float* Ub    = (const float*)d_in[16];
  const float* bb    = (const float*)d_in[17];
  const float* Wn    = (const float*)d_in[18];
  const float* Un    = (const float*)d_in[19];
  const float* bn    = (const float*)d_in[20];
  const float* rW1   = (const float*)d_in[21];
  const float* rb1   = (const float*)d_in[22];
  const float* rW2   = (const float*)d_in[23];
  const float* rb2   = (const float*)d_in[24];
  const float* rW3   = (const float*)d_in[25];
  const float* rb3   = (const float*)d_in[26];
  const int* paths   = (const int*)d_in[27];
  const int* seqs    = (const int*)d_in[28];
  const int* nodes   = (const int*)d_in[29];
  const int* adj_idx = (const int*)d_in[30];
  int E = in_sizes[27];

  char* w0 = (char*)d_ws;
  char* w = w0;
  auto alloc = [&](size_t nbytes)->void*{ void* r=(void*)w; w += (nbytes + 255) & ~(size_t)255; return r; };
  float* ns     = (float*)alloc((size_t)NN*DD*4);
  float* gout   = (float*)alloc((size_t)NN*DD*4);
  float* psA    = (float*)alloc((size_t)NP*DD*4);
  float* psB    = (float*)alloc((size_t)NP*DD*4);
  ushort_t* xpTh= (ushort_t*)alloc((size_t)NHD*NN*2);
  ushort_t* xpTl= (ushort_t*)alloc((size_t)NHD*NN*2);
  float* es     = (float*)alloc((size_t)NN*NH*4);
  float* en     = (float*)alloc((size_t)NN*NH*4);
  unsigned int* adjb = (unsigned int*)alloc((size_t)NN*16*4);
  float* xgp    = (float*)alloc((size_t)NN*G3*4);
  float* xgb    = (float*)alloc((size_t)NN*G3*4);
  float* m2     = (float*)alloc((size_t)NN*DD*4);
  float* bxgF   = (float*)alloc((size_t)G3*4);
  float* bxgB   = (float*)alloc((size_t)G3*4);
  float* gbUn   = (float*)alloc((size_t)G3*4);
  ushort_t* Uthp = (ushort_t*)alloc((size_t)G3*DD*2);
  ushort_t* Utlp = (ushort_t*)alloc((size_t)G3*DD*2);
  ushort_t* Uthb = (ushort_t*)alloc((size_t)G3*DD*2);
  ushort_t* Utlb = (ushort_t*)alloc((size_t)G3*DD*2);
  ushort_t* Wpth = (ushort_t*)alloc((size_t)G3*DD*2);
  ushort_t* Wptl = (ushort_t*)alloc((size_t)G3*DD*2);
  ushort_t* Wbth = (ushort_t*)alloc((size_t)G3*DD*2);
  ushort_t* Wbtl = (ushort_t*)alloc((size_t)G3*DD*2);
  ushort_t* WnTh = (ushort_t*)alloc((size_t)G3*DD*2);
  ushort_t* WnTl = (ushort_t*)alloc((size_t)G3*DD*2);
  ushort_t* UnTh = (ushort_t*)alloc((size_t)G3*DD*2);
  ushort_t* UnTl = (ushort_t*)alloc((size_t)G3*DD*2);
  ushort_t* r1h = (ushort_t*)alloc((size_t)256*128*2);
  ushort_t* r1l = (ushort_t*)alloc((size_t)256*128*2);
  ushort_t* r2h = (ushort_t*)alloc((size_t)256*256*2);
  ushort_t* r2l = (ushort_t*)alloc((size_t)256*256*2);
  ushort_t* gwh = (ushort_t*)alloc((size_t)NHD*DD*2);
  ushort_t* gwl = (ushort_t*)alloc((size_t)NHD*DD*2);
  int* start    = (int*)alloc((size_t)NP*4);
  int* lens     = (int*)alloc((size_t)NP*4);
  int* perm     = (int*)alloc((size_t)NP*4);
  int* lcnt     = (int*)alloc(16*4);
  int* loff     = (int*)alloc(16*4);
  int* lcur     = (int*)alloc(16*4);
  (void)n_in; (void)out_size; (void)ws_size;

  hipMemsetAsync(adjb, 0, (size_t)NN*16*4, stream);
  hipMemsetAsync(lcnt, 0, 16*4, stream);
  k_init_ns<<<NN,DD,0,stream>>>(ns, qpol, w1, w2, w3, qs);
  k_init_ps<<<(NP*DD+255)/256,256,0,stream>>>(psA, bw, ToS);
  k_adj<<<16,256,0,stream>>>(adjb, adj_idx, lc);
  k_meta<<<(E+255)/256,256,0,stream>>>(paths, seqs, start, lens, E);
  k_lcount<<<(NP+255)/256,256,0,stream>>>(lens, lcnt);
  k_lscan<<<1,64,0,stream>>>(lcnt, loff, lcur);
  k_lfill<<<(NP+255)/256,256,0,stream>>>(lens, lcur, perm);
  k_wsplit6<<<(6*G3*DD+255)/256,256,0,stream>>>(Up, Ub, Wp, Wb, Wn, Un,
      Uthp,Utlp, Uthb,Utlb, Wpth,Wptl, Wbth,Wbtl, WnTh,WnTl, UnTh,UnTl);
  k_wsplit<<<(256*128+255)/256,256,0,stream>>>(rW1, r1h, r1l, 7, 256, 256*128);
  k_wsplit<<<(256*256+255)/256,256,0,stream>>>(rW2, r2h, r2l, 8, 256, 256*256);
  k_wsplit<<<(NHD*DD+255)/256,256,0,stream>>>(gat_W, gwh, gwl, 7, NHD, NHD*DD);
  k_gbw<<<3,G3,0,stream>>>(gat_b, Wp, Wb, Un, bp, bb, bxgF, bxgB, gbUn);

  float* ps_cur = psA; float* ps_nxt = psB;
  for (int t=0;t<3;t++){
    hipMemsetAsync(gout, 0, (size_t)NN*DD*4, stream);
    k_xp2<<<dim3(NN/32, NHD/256),512,0,stream>>>(ns, gwh, gwl, gat_as, gat_an, xpTh, xpTl, es, en);
    k_attn2<<<dim3(NH, NN/32),256,0,stream>>>(xpTh, xpTl, es, en, adjb, gout);
    k_xg3<<<dim3(NN/32,6),512,0,stream>>>(gout, Wpth, Wptl, Wbth, Wbtl, bxgF, bxgB, xgp, xgb);
    hipMemsetAsync(m2, 0, (size_t)NN*DD*4, stream);
    k_gru2<<<2*(NP/32),512,0,stream>>>(ps_cur, ps_nxt, xgp, xgb, Uthp, Utlp, Uthb, Utlb,
                                       bp+G3, bb+G3, start, lens, nodes, perm, m2);
    k_ngru3<<<NN/32,512,0,stream>>>(m2, gout, WnTh, WnTl, UnTh, UnTl, bn, gat_b, gbUn, ns);
    float* tmp = ps_cur; ps_cur = ps_nxt; ps_nxt = tmp;
  }
  k_read2<<<NP/32,512,0,stream>>>(ps_cur, r1h, r1l, r2h, r2l, rb1, rb2, rW3, rb3, (float*)d_out);
}

// Round 11
// 1057.153 us; speedup vs baseline: 1.4393x; 1.4393x over previous
//
#include <hip/hip_runtime.h>
#include <math.h>

#define NN 512
#define NP 20000
#define DD 128
#define NH 24
#define G3 384
#define NHD 3072  /* NH*DD */

typedef __attribute__((ext_vector_type(8))) short bf8_t;   /* 8 bf16 */
typedef __attribute__((ext_vector_type(4))) float f4_t;
typedef unsigned short ushort_t;

/* fast transcendentals */
__device__ __forceinline__ float sigf(float x){
  return __builtin_amdgcn_rcpf(1.f + __expf(-x));
}
__device__ __forceinline__ float tanh_fast(float x){
  float ax = fabsf(x);
  float e = __expf(-2.f*ax);
  float t = (1.f - e) * __builtin_amdgcn_rcpf(1.f + e);
  return copysignf(t, x);
}
__device__ __forceinline__ unsigned short f2bf(float f){
  unsigned int u = __float_as_uint(f);
  unsigned int r = (u + 0x7fffu + ((u>>16)&1u)) >> 16;
  return (unsigned short)r;
}
__device__ __forceinline__ float bf2f(unsigned short h){
  return __uint_as_float(((unsigned int)h)<<16);
}

/* ---------------- init ---------------- */
__global__ void k_init_ns(float* ns, const float* qp, const float* w1, const float* w2,
                          const float* w3, const float* qs){
  int n = blockIdx.x, c = threadIdx.x;
  float v = 0.f;
  if (c==0) v=qp[n]; else if (c==1) v=w1[n]; else if (c==2) v=w2[n]; else if (c==3) v=w3[n];
  else if (c<7) v=qs[n*3 + (c-4)];
  ns[n*DD+c]=v;
}

__global__ void k_init_ps(float* ps, const float* bw, const float* tos){
  int i = blockIdx.x*256 + threadIdx.x;
  if (i >= NP*DD) return;
  int p = i>>7, c = i&127;
  float v=0.f; if(c==0) v=bw[p]; else if(c==1) v=tos[p];
  ps[i]=v;
}

/* adjacency as bitmask */
__global__ void k_adj(unsigned int* adjb, const int* idx, const float* lc){
  int l = blockIdx.x*256+threadIdx.x; if(l>=4096) return;
  if (lc[l]!=0.f){
    int a = idx[l]; int i = a>>9, j = a&511;
    atomicOr(&adjb[i*16 + (j>>5)], 1u<<(j&31));
  }
}

__global__ void k_meta(const int* paths, const int* seqs, int* start, int* lens, int E){
  int e = blockIdx.x*256+threadIdx.x; if(e>=E) return;
  int p=paths[e], s=seqs[e];
  if (s==0) start[p]=e;
  if (e==E-1 || paths[e+1]!=p) lens[p]=s+1;
}

/* ---- length sort (counting sort, descending) ---- */
__global__ void k_lcount(const int* __restrict__ lens, int* lcnt){
  int p = blockIdx.x*256+threadIdx.x; if(p>=NP) return;
  atomicAdd(&lcnt[lens[p]],1);
}
__global__ void k_lscan(const int* __restrict__ lcnt, int* loff, int* lcur){
  if (threadIdx.x==0){
    int acc=0;
    for (int L=15; L>=0; --L){ loff[L]=acc; lcur[L]=acc; acc+=lcnt[L]; }
  }
}
__global__ void k_lfill(const int* __restrict__ lens, int* lcur, int* perm){
  int p = blockIdx.x*256+threadIdx.x; if(p>=NP) return;
  int pos = atomicAdd(&lcur[lens[p]],1);
  perm[pos]=p;
}

/* transpose+split: W [K][ncols] -> Wt hi/lo [ncols][K], K = 1<<shift */
__global__ void k_wsplit(const float* __restrict__ W, ushort_t* __restrict__ Wh,
                         ushort_t* __restrict__ Wl, int shift, int ncols, int total){
  int i = blockIdx.x*256 + threadIdx.x;
  if (i >= total) return;
  int col = i >> shift, k = i & ((1<<shift)-1);
  float v = W[(size_t)k*ncols + col];
  ushort_t h = f2bf(v);
  Wh[i] = h; Wl[i] = f2bf(v - bf2f(h));
}

/* batch split for the six G3xDD matrices */
__global__ void k_wsplit6(
    const float* S0,const float* S1,const float* S2,const float* S3,const float* S4,const float* S5,
    ushort_t* H0, ushort_t* L0, ushort_t* H1, ushort_t* L1, ushort_t* H2, ushort_t* L2,
    ushort_t* H3, ushort_t* L3, ushort_t* H4, ushort_t* L4, ushort_t* H5, ushort_t* L5){
  int i = blockIdx.x*256 + threadIdx.x;
  if (i >= 6*G3*DD) return;
  int m = i/(G3*DD), r = i - m*(G3*DD);
  const float* S = m==0?S0:m==1?S1:m==2?S2:m==3?S3:m==4?S4:S5;
  ushort_t* Hh = m==0?H0:m==1?H1:m==2?H2:m==3?H3:m==4?H4:H5;
  ushort_t* Ll = m==0?L0:m==1?L1:m==2?L2:m==3?L3:m==4?L4:L5;
  int col = r>>7, k = r&127;
  float v = S[(size_t)k*G3 + col];
  ushort_t h = f2bf(v);
  Hh[r] = h; Ll[r] = f2bf(v - bf2f(h));
}

/* bias folds: bxgF = bp + gb@Wp ; bxgB = bb + gb@Wb ; gbUn = gb@Un */
__global__ void k_gbw(const float* __restrict__ gb,
                      const float* __restrict__ Wp, const float* __restrict__ Wb,
                      const float* __restrict__ Un,
                      const float* __restrict__ bp, const float* __restrict__ bb,
                      float* bxgF, float* bxgB, float* gbUn){
  int m = blockIdx.x; int j = threadIdx.x; /* 384 threads */
  const float* W = m==0?Wp:(m==1?Wb:Un);
  float a = m==0?bp[j]:(m==1?bb[j]:0.f);
  for (int k=0;k<128;k++) a += gb[k]*W[(size_t)k*G3+j];
  (m==0?bxgF:(m==1?bxgB:gbUn))[j]=a;
}

/* ---------------- GAT: xp GEMM -> xpT (bf16 split, [col][node]) + fused es/en ---------------- */
__global__ __launch_bounds__(512) void k_xp2(const float* __restrict__ ns,
                      const ushort_t* __restrict__ gwh, const ushort_t* __restrict__ gwl,
                      const float* __restrict__ as_, const float* __restrict__ an_,
                      ushort_t* __restrict__ xpTh, ushort_t* __restrict__ xpTl,
                      float* __restrict__ es, float* __restrict__ en){
  __shared__ __align__(16) ushort_t XsH[32][136], XsL[32][136];
  __shared__ float ered[8][32][2];   /* [wave][row][es/en] partials */
  int r0 = blockIdx.x*32, c0 = blockIdx.y*256;
  int tid = threadIdx.x;
  int w = tid>>6, l = tid&63, lr = l&15, lg = l>>4;
  for (int idx=tid; idx<32*128; idx+=512){
    int pp=idx>>7, kk=idx&127;
    float v = ns[(size_t)(r0+pp)*DD+kk];
    ushort_t hi=f2bf(v); XsH[pp][kk]=hi; XsL[pp][kk]=f2bf(v-bf2f(hi));
  }
  __syncthreads();
  int col0 = c0 + w*32 + lr, col1 = col0 + 16;
  f4_t a00=(f4_t)(0.f), a01=(f4_t)(0.f), a10=(f4_t)(0.f), a11=(f4_t)(0.f);
  #pragma unroll
  for (int kt=0; kt<4; kt++){
    int kof = kt*32 + lg*8;
    const bf8_t Ah0 = *(const bf8_t*)&XsH[lr][kof];
    const bf8_t Al0 = *(const bf8_t*)&XsL[lr][kof];
    const bf8_t Ah1 = *(const bf8_t*)&XsH[16+lr][kof];
    const bf8_t Al1 = *(const bf8_t*)&XsL[16+lr][kof];
    const bf8_t B0h = *(const bf8_t*)(gwh + (size_t)col0*128 + kof);
    const bf8_t B0l = *(const bf8_t*)(gwl + (size_t)col0*128 + kof);
    const bf8_t B1h = *(const bf8_t*)(gwh + (size_t)col1*128 + kof);
    const bf8_t B1l = *(const bf8_t*)(gwl + (size_t)col1*128 + kof);
    a00 = __builtin_amdgcn_mfma_f32_16x16x32_bf16(Ah0,B0h,a00,0,0,0);
    a00 = __builtin_amdgcn_mfma_f32_16x16x32_bf16(Al0,B0h,a00,0,0,0);
    a00 = __builtin_amdgcn_mfma_f32_16x16x32_bf16(Ah0,B0l,a00,0,0,0);
    a01 = __builtin_amdgcn_mfma_f32_16x16x32_bf16(Ah0,B1h,a01,0,0,0);
    a01 = __builtin_amdgcn_mfma_f32_16x16x32_bf16(Al0,B1h,a01,0,0,0);
    a01 = __builtin_amdgcn_mfma_f32_16x16x32_bf16(Ah0,B1l,a01,0,0,0);
    a10 = __builtin_amdgcn_mfma_f32_16x16x32_bf16(Ah1,B0h,a10,0,0,0);
    a10 = __builtin_amdgcn_mfma_f32_16x16x32_bf16(Al1,B0h,a10,0,0,0);
    a10 = __builtin_amdgcn_mfma_f32_16x16x32_bf16(Ah1,B0l,a10,0,0,0);
    a11 = __builtin_amdgcn_mfma_f32_16x16x32_bf16(Ah1,B1h,a11,0,0,0);
    a11 = __builtin_amdgcn_mfma_f32_16x16x32_bf16(Al1,B1h,a11,0,0,0);
    a11 = __builtin_amdgcn_mfma_f32_16x16x32_bf16(Ah1,B1l,a11,0,0,0);
  }
  /* store transposed split-bf16: xpT[col][node]; 4 consecutive nodes packed */
  {
    ushort4 h00,l00,h01,l01,h10,l10,h11,l11;
    #pragma unroll
    for (int q=0;q<4;q++){
      float v; ushort_t hh;
      v=a00[q]; hh=f2bf(v); ((ushort_t*)&h00)[q]=hh; ((ushort_t*)&l00)[q]=f2bf(v-bf2f(hh));
      v=a01[q]; hh=f2bf(v); ((ushort_t*)&h01)[q]=hh; ((ushort_t*)&l01)[q]=f2bf(v-bf2f(hh));
      v=a10[q]; hh=f2bf(v); ((ushort_t*)&h10)[q]=hh; ((ushort_t*)&l10)[q]=f2bf(v-bf2f(hh));
      v=a11[q]; hh=f2bf(v); ((ushort_t*)&h11)[q]=hh; ((ushort_t*)&l11)[q]=f2bf(v-bf2f(hh));
    }
    size_t b0 = (size_t)col0*NN + r0 + lg*4;
    size_t b1 = (size_t)col1*NN + r0 + lg*4;
    *(ushort4*)(xpTh + b0)      = h00; *(ushort4*)(xpTl + b0)      = l00;
    *(ushort4*)(xpTh + b1)      = h01; *(ushort4*)(xpTl + b1)      = l01;
    *(ushort4*)(xpTh + b0 + 16) = h10; *(ushort4*)(xpTl + b0 + 16) = l10;
    *(ushort4*)(xpTh + b1 + 16) = h11; *(ushort4*)(xpTl + b1 + 16) = l11;
  }
  /* es/en partials: wave w covers one head hw, cols [w*32, w*32+32) */
  {
    int hw = blockIdx.y*2 + (w>>2);
    int cc0 = (w*32 + lr)&127, cc1 = (w*32 + 16 + lr)&127;
    float as0 = as_[hw*DD+cc0], as1 = as_[hw*DD+cc1];
    float an0 = an_[hw*DD+cc0], an1 = an_[hw*DD+cc1];
    #pragma unroll
    for (int q=0;q<4;q++){
      float s0 = a00[q]*as0 + a01[q]*as1;
      float n0 = a00[q]*an0 + a01[q]*an1;
      float s1 = a10[q]*as0 + a11[q]*as1;
      float n1 = a10[q]*an0 + a11[q]*an1;
      #pragma unroll
      for (int o=1;o<16;o<<=1){
        s0 += __shfl_xor(s0,o); n0 += __shfl_xor(n0,o);
        s1 += __shfl_xor(s1,o); n1 += __shfl_xor(n1,o);
      }
      if (lr==0){
        ered[w][lg*4+q][0]=s0;    ered[w][lg*4+q][1]=n0;
        ered[w][16+lg*4+q][0]=s1; ered[w][16+lg*4+q][1]=n1;
      }
    }
  }
  __syncthreads();
  if (tid < 128){
    int row = tid&31, hh = (tid>>5)&1, which = tid>>6;
    float v = ered[hh*4+0][row][which] + ered[hh*4+1][row][which]
            + ered[hh*4+2][row][which] + ered[hh*4+3][row][which];
    float* dst = which? en : es;
    dst[(size_t)(r0+row)*NH + blockIdx.y*2 + hh] = v;
  }
}

/* attn: max pass + single-exp pass (unnormalized P), MFMA PV, 1/s folded in epilogue */
__global__ __launch_bounds__(256) void k_attn2(
    const ushort_t* __restrict__ xpTh, const ushort_t* __restrict__ xpTl,
    const float* __restrict__ es, const float* __restrict__ en,
    const unsigned int* __restrict__ adjb, float* __restrict__ gout)
{
  __shared__ __align__(16) ushort_t PsH[32][520], PsL[32][520];
  __shared__ float enl[512], esl[32];
  __shared__ unsigned int am[32][16];
  __shared__ float isms[32];
  int h = blockIdx.x, i0 = blockIdx.y*32, tid = threadIdx.x;
  for (int j=tid; j<512; j+=256) enl[j] = en[(size_t)j*NH + h];
  for (int idx=tid; idx<512; idx+=256) am[idx>>4][idx&15] = adjb[(i0+(idx>>4))*16 + (idx&15)];
  if (tid<32) esl[tid] = es[(size_t)(i0+tid)*NH + h];
  __syncthreads();
  {
    int t8 = tid&7, ii = tid>>3;
    float esr = esl[ii];
    /* pass 1: max only */
    float m = -INFINITY;
    for (int j=t8; j<512; j+=8){
      float lv = esr + enl[j];
      lv = (lv>=0.f)? lv : 0.2f*lv;
      if (!((am[ii][j>>5]>>(j&31))&1u)) lv = -1000000000.0f;
      m = fmaxf(m, lv);
    }
    #pragma unroll
    for (int o=4;o>0;o>>=1) m = fmaxf(m, __shfl_xor(m,o));
    /* pass 2: single exp, store unnormalized split-bf16 P, register sum */
    float s = 0.f;
    for (int j=t8; j<512; j+=8){
      float lv = esr + enl[j];
      lv = (lv>=0.f)? lv : 0.2f*lv;
      if (!((am[ii][j>>5]>>(j&31))&1u)) lv = -1000000000.0f;
      float e = __expf(lv - m);
      s += e;
      ushort_t hi = f2bf(e);
      PsH[ii][j] = hi; PsL[ii][j] = f2bf(e - bf2f(hi));
    }
    #pragma unroll
    for (int o=4;o>0;o>>=1) s += __shfl_xor(s,o);
    if (t8==0) isms[ii] = __builtin_amdgcn_rcpf(s);
  }
  __syncthreads();
  /* PV via MFMA: P(32x512) @ xpT_h(512x128); wave wv owns cols [wv*32, wv*32+32) */
  int wv = tid>>6, ln = tid&63, lr = ln&15, lg = ln>>4;
  const ushort_t* B0hp = xpTh + ((size_t)(h*DD + wv*32 + lr))*NN;
  const ushort_t* B0lp = xpTl + ((size_t)(h*DD + wv*32 + lr))*NN;
  const ushort_t* B1hp = B0hp + (size_t)16*NN;
  const ushort_t* B1lp = B0lp + (size_t)16*NN;
  f4_t a00=(f4_t)(0.f), a01=(f4_t)(0.f), a10=(f4_t)(0.f), a11=(f4_t)(0.f);
  #pragma unroll
  for (int kt=0; kt<16; kt++){
    int kof = kt*32 + lg*8;
    const bf8_t A0h = *(const bf8_t*)&PsH[lr][kof];
    const bf8_t A0l = *(const bf8_t*)&PsL[lr][kof];
    const bf8_t A1h = *(const bf8_t*)&PsH[16+lr][kof];
    const bf8_t A1l = *(const bf8_t*)&PsL[16+lr][kof];
    const bf8_t B0h = *(const bf8_t*)(B0hp + kof);
    const bf8_t B0l = *(const bf8_t*)(B0lp + kof);
    const bf8_t B1h = *(const bf8_t*)(B1hp + kof);
    const bf8_t B1l = *(const bf8_t*)(B1lp + kof);
    a00 = __builtin_amdgcn_mfma_f32_16x16x32_bf16(A0h,B0h,a00,0,0,0);
    a00 = __builtin_amdgcn_mfma_f32_16x16x32_bf16(A0l,B0h,a00,0,0,0);
    a00 = __builtin_amdgcn_mfma_f32_16x16x32_bf16(A0h,B0l,a00,0,0,0);
    a01 = __builtin_amdgcn_mfma_f32_16x16x32_bf16(A0h,B1h,a01,0,0,0);
    a01 = __builtin_amdgcn_mfma_f32_16x16x32_bf16(A0l,B1h,a01,0,0,0);
    a01 = __builtin_amdgcn_mfma_f32_16x16x32_bf16(A0h,B1l,a01,0,0,0);
    a10 = __builtin_amdgcn_mfma_f32_16x16x32_bf16(A1h,B0h,a10,0,0,0);
    a10 = __builtin_amdgcn_mfma_f32_16x16x32_bf16(A1l,B0h,a10,0,0,0);
    a10 = __builtin_amdgcn_mfma_f32_16x16x32_bf16(A1h,B0l,a10,0,0,0);
    a11 = __builtin_amdgcn_mfma_f32_16x16x32_bf16(A1h,B1h,a11,0,0,0);
    a11 = __builtin_amdgcn_mfma_f32_16x16x32_bf16(A1l,B1h,a11,0,0,0);
    a11 = __builtin_amdgcn_mfma_f32_16x16x32_bf16(A1h,B1l,a11,0,0,0);
  }
  const float inv = 1.f/24.f;
  #pragma unroll
  for (int q=0;q<4;q++){
    int r0w = lg*4+q, r1w = 16+lg*4+q;
    float s0 = isms[r0w]*inv, s1 = isms[r1w]*inv;
    atomicAdd(&gout[(size_t)(i0+r0w)*DD + wv*32 + lr],      a00[q]*s0);
    atomicAdd(&gout[(size_t)(i0+r0w)*DD + wv*32 + 16 + lr], a01[q]*s0);
    atomicAdd(&gout[(size_t)(i0+r1w)*DD + wv*32 + lr],      a10[q]*s1);
    atomicAdd(&gout[(size_t)(i0+r1w)*DD + wv*32 + 16 + lr], a11[q]*s1);
  }
}

/* xg for both dirs via MFMA; bias vector includes gb@W fold */
__global__ __launch_bounds__(512) void k_xg3(const float* __restrict__ gout,
      const ushort_t* __restrict__ WpH, const ushort_t* __restrict__ WpL,
      const ushort_t* __restrict__ WbH, const ushort_t* __restrict__ WbL,
      const float* __restrict__ bxgF, const float* __restrict__ bxgB,
      float* __restrict__ xgF, float* __restrict__ xgB){
  __shared__ __align__(16) ushort_t XsH[32][136], XsL[32][136];
  int r0 = blockIdx.x*32;
  int mat = blockIdx.y/3, cg = blockIdx.y%3;
  const ushort_t* Wh = mat? WbH : WpH;
  const ushort_t* Wl = mat? WbL : WpL;
  const float* b0 = mat? bxgB : bxgF;
  float* out = mat? xgB : xgF;
  int tid = threadIdx.x;
  int w = tid>>6, l = tid&63, lr = l&15, lg = l>>4;
  for (int idx=tid; idx<32*128; idx+=512){
    int pp=idx>>7, kk=idx&127;
    float v = gout[(size_t)(r0+pp)*DD+kk];
    ushort_t hi=f2bf(v); XsH[pp][kk]=hi; XsL[pp][kk]=f2bf(v-bf2f(hi));
  }
  __syncthreads();
  int col = cg*128 + w*16 + lr;
  f4_t a0=(f4_t)(0.f), a1=(f4_t)(0.f);
  #pragma unroll
  for (int kt=0; kt<4; kt++){
    int kof = kt*32 + lg*8;
    const bf8_t Ah0 = *(const bf8_t*)&XsH[lr][kof];
    const bf8_t Al0 = *(const bf8_t*)&XsL[lr][kof];
    const bf8_t Ah1 = *(const bf8_t*)&XsH[16+lr][kof];
    const bf8_t Al1 = *(const bf8_t*)&XsL[16+lr][kof];
    const bf8_t Bh = *(const bf8_t*)(Wh + (size_t)col*128 + kof);
    const bf8_t Bl = *(const bf8_t*)(Wl + (size_t)col*128 + kof);
    a0 = __builtin_amdgcn_mfma_f32_16x16x32_bf16(Ah0,Bh,a0,0,0,0);
    a0 = __builtin_amdgcn_mfma_f32_16x16x32_bf16(Al0,Bh,a0,0,0,0);
    a0 = __builtin_amdgcn_mfma_f32_16x16x32_bf16(Ah0,Bl,a0,0,0,0);
    a1 = __builtin_amdgcn_mfma_f32_16x16x32_bf16(Ah1,Bh,a1,0,0,0);
    a1 = __builtin_amdgcn_mfma_f32_16x16x32_bf16(Al1,Bh,a1,0,0,0);
    a1 = __builtin_amdgcn_mfma_f32_16x16x32_bf16(Ah1,Bl,a1,0,0,0);
  }
  float bb0 = b0[col];
  #pragma unroll
  for (int q=0;q<4;q++){
    out[(size_t)(r0+lg*4+q)*G3 + col]    = a0[q] + bb0;
    out[(size_t)(r0+16+lg*4+q)*G3 + col] = a1[q] + bb0;
  }
}

/* ---------------- fused bidirectional path GRU (split-bf16 MFMA, 32 paths) ---------------- */
__global__ __launch_bounds__(512) void k_gru2(
    const float* __restrict__ ps_in, float* __restrict__ ps_out,
    const float* __restrict__ xgF, const float* __restrict__ xgB,
    const ushort_t* __restrict__ UthF, const ushort_t* __restrict__ UtlF,
    const ushort_t* __restrict__ UthB, const ushort_t* __restrict__ UtlB,
    const float* __restrict__ b1F, const float* __restrict__ b1B,
    const int* __restrict__ start, const int* __restrict__ lens,
    const int* __restrict__ nodes, const int* __restrict__ perm,
    float* __restrict__ m2)
{
  __shared__ __align__(16) ushort_t HsH[2][32][136];
  __shared__ __align__(16) ushort_t HsL[2][32][136];
  __shared__ int Ls[32], Ss[32], Pid[32];
  __shared__ int nid_l[32][8];

  int dir = blockIdx.x & 1, pblk = blockIdx.x >> 1;
  const bool rev = (dir==1);
  const float* xg = rev ? xgB : xgF;
  const ushort_t* Uth = rev ? UthB : UthF;
  const ushort_t* Utl = rev ? UtlB : UtlF;
  const float* b1 = rev ? b1B : b1F;
  float* psn = rev ? (float*)0 : ps_out;

  int pb = pblk*32;
  int tid = threadIdx.x;
  int w = tid>>6, l = tid&63;
  int lr = l&15, lg = l>>4;
  int c = w*16 + lr;

  if (tid<32){ int pid = perm[pb+tid]; Pid[tid]=pid; Ls[tid]=lens[pid]; Ss[tid]=start[pid]; }
  __syncthreads();
  for (int idx=tid; idx<32*128; idx+=512){
    int pp=idx>>7, kk=idx&127;
    float v = ps_in[(size_t)Pid[pp]*DD+kk];
    ushort_t hi = f2bf(v);
    HsH[0][pp][kk]=hi; HsL[0][pp][kk]=f2bf(v - bf2f(hi));
  }
  if (tid<256){
    int p=tid>>3, s=tid&7; int L=Ls[p];
    int nid = 0;
    if (s<L){ int pos = rev ? (L-1-s) : s; nid = nodes[Ss[p]+pos]; }
    nid_l[p][s]=nid;
  }
  __syncthreads();

  int Lmax = Ls[0];
  int Lv[8];
  #pragma unroll
  for (int i=0;i<8;i++){ int p=(i>>2)*16 + lg*4 + (i&3); Lv[i]=Ls[p]; }
  float b1z = b1[c], b1r = b1[128+c], b1h = b1[256+c];

  int cur = 0;
  for (int s=0;s<Lmax;s++){
    int nxt = cur^1;
    bool act[8]; int niv[8]; float xzv[8], xrv[8], xhv[8];
    #pragma unroll
    for (int i=0;i<8;i++){
      int p=(i>>2)*16 + lg*4 + (i&3);
      act[i] = (s < Lv[i]);
      int nid = nid_l[p][s];
      niv[i] = nid;
      const float* xr = xg + (size_t)nid*G3;
      xzv[i]=xr[c]; xrv[i]=xr[128+c]; xhv[i]=xr[256+c];
    }
    f4_t accz0=(f4_t)(0.f), accz1=(f4_t)(0.f);
    f4_t accr0=(f4_t)(0.f), accr1=(f4_t)(0.f);
    f4_t acch0=(f4_t)(0.f), acch1=(f4_t)(0.f);
    #pragma unroll
    for (int kt=0; kt<4; kt++){
      int kof = kt*32 + lg*8;
      const bf8_t Ahi0 = *(const bf8_t*)&HsH[cur][lr][kof];
      const bf8_t Alo0 = *(const bf8_t*)&HsL[cur][lr][kof];
      const bf8_t Ahi1 = *(const bf8_t*)&HsH[cur][16+lr][kof];
      const bf8_t Alo1 = *(const bf8_t*)&HsL[cur][16+lr][kof];
      const bf8_t Bhz = *(const bf8_t*)(Uth + ((size_t)(      c))*128 + kof);
      const bf8_t Blz = *(const bf8_t*)(Utl + ((size_t)(      c))*128 + kof);
      const bf8_t Bhr = *(const bf8_t*)(Uth + ((size_t)(128 + c))*128 + kof);
      const bf8_t Blr = *(const bf8_t*)(Utl + ((size_t)(128 + c))*128 + kof);
      const bf8_t Bhh = *(const bf8_t*)(Uth + ((size_t)(256 + c))*128 + kof);
      const bf8_t Blh = *(const bf8_t*)(Utl + ((size_t)(256 + c))*128 + kof);
      accz0 = __builtin_amdgcn_mfma_f32_16x16x32_bf16(Ahi0, Bhz, accz0, 0,0,0);
      accz0 = __builtin_amdgcn_mfma_f32_16x16x32_bf16(Alo0, Bhz, accz0, 0,0,0);
      accz0 = __builtin_amdgcn_mfma_f32_16x16x32_bf16(Ahi0, Blz, accz0, 0,0,0);
      accz1 = __builtin_amdgcn_mfma_f32_16x16x32_bf16(Ahi1, Bhz, accz1, 0,0,0);
      accz1 = __builtin_amdgcn_mfma_f32_16x16x32_bf16(Alo1, Bhz, accz1, 0,0,0);
      accz1 = __builtin_amdgcn_mfma_f32_16x16x32_bf16(Ahi1, Blz, accz1, 0,0,0);
      accr0 = __builtin_amdgcn_mfma_f32_16x16x32_bf16(Ahi0, Bhr, accr0, 0,0,0);
      accr0 = __builtin_amdgcn_mfma_f32_16x16x32_bf16(Alo0, Bhr, accr0, 0,0,0);
      accr0 = __builtin_amdgcn_mfma_f32_16x16x32_bf16(Ahi0, Blr, accr0, 0,0,0);
      accr1 = __builtin_amdgcn_mfma_f32_16x16x32_bf16(Ahi1, Bhr, accr1, 0,0,0);
      accr1 = __builtin_amdgcn_mfma_f32_16x16x32_bf16(Alo1, Bhr, accr1, 0,0,0);
      accr1 = __builtin_amdgcn_mfma_f32_16x16x32_bf16(Ahi1, Blr, accr1, 0,0,0);
      acch0 = __builtin_amdgcn_mfma_f32_16x16x32_bf16(Ahi0, Bhh, acch0, 0,0,0);
      acch0 = __builtin_amdgcn_mfma_f32_16x16x32_bf16(Alo0, Bhh, acch0, 0,0,0);
      acch0 = __builtin_amdgcn_mfma_f32_16x16x32_bf16(Ahi0, Blh, acch0, 0,0,0);
      acch1 = __builtin_amdgcn_mfma_f32_16x16x32_bf16(Ahi1, Bhh, acch1, 0,0,0);
      acch1 = __builtin_amdgcn_mfma_f32_16x16x32_bf16(Alo1, Bhh, acch1, 0,0,0);
      acch1 = __builtin_amdgcn_mfma_f32_16x16x32_bf16(Ahi1, Blh, acch1, 0,0,0);
    }
#define EPI(i, mt, qq, AZ, AR, AH) { \
    int p = (mt)*16 + lg*4 + (qq); \
    if (act[i]) { \
      float hold = bf2f(HsH[cur][p][c]) + bf2f(HsL[cur][p][c]); \
      float z = sigf(xzv[i] + (AZ) + b1z); \
      float r = sigf(xrv[i] + (AR) + b1r); \
      float hc = tanh_fast(xhv[i] + r*((AH) + b1h)); \
      float hn = z*hold + (1.f-z)*hc; \
      ushort_t hi2 = f2bf(hn); \
      HsH[nxt][p][c]=hi2; HsL[nxt][p][c]=f2bf(hn - bf2f(hi2)); \
      atomicAdd(&m2[(size_t)niv[i]*DD + c], hn); \
    } else { \
      HsH[nxt][p][c]=HsH[cur][p][c]; HsL[nxt][p][c]=HsL[cur][p][c]; \
    } }
    EPI(0,0,0, accz0.x, accr0.x, acch0.x)
    EPI(1,0,1, accz0.y, accr0.y, acch0.y)
    EPI(2,0,2, accz0.z, accr0.z, acch0.z)
    EPI(3,0,3, accz0.w, accr0.w, acch0.w)
    EPI(4,1,0, accz1.x, accr1.x, acch1.x)
    EPI(5,1,1, accz1.y, accr1.y, acch1.y)
    EPI(6,1,2, accz1.z, accr1.z, acch1.z)
    EPI(7,1,3, accz1.w, accr1.w, acch1.w)
#undef EPI
    __syncthreads();
    cur = nxt;
  }
  if (psn){
    for (int idx=tid; idx<32*128; idx+=512){
      int pp=idx>>7, kk=idx&127;
      psn[(size_t)Pid[pp]*DD+kk] = bf2f(HsH[cur][pp][kk]) + bf2f(HsL[cur][pp][kk]);
    }
  }
}

/* ---------------- node GRU via MFMA (bias folds) ---------------- */
__global__ __launch_bounds__(512) void k_ngru3(
    const float* __restrict__ m2, const float* __restrict__ gout,
    const ushort_t* __restrict__ WnH, const ushort_t* __restrict__ WnL,
    const ushort_t* __restrict__ UnH, const ushort_t* __restrict__ UnL,
    const float* __restrict__ bn, const float* __restrict__ gb,
    const float* __restrict__ gbUn, float* __restrict__ ns)
{
  __shared__ __align__(16) ushort_t MsH[32][136], MsL[32][136];
  __shared__ __align__(16) ushort_t GsH[32][136], GsL[32][136];
  int r0 = blockIdx.x*32;
  int tid = threadIdx.x;
  int w = tid>>6, l = tid&63, lr = l&15, lg = l>>4;
  for (int idx=tid; idx<32*128; idx+=512){
    int pp=idx>>7, kk=idx&127;
    float vm = m2[(size_t)(r0+pp)*DD+kk];
    float vg = gout[(size_t)(r0+pp)*DD+kk];
    ushort_t hm=f2bf(vm); MsH[pp][kk]=hm; MsL[pp][kk]=f2bf(vm-bf2f(hm));
    ushort_t hg=f2bf(vg); GsH[pp][kk]=hg; GsL[pp][kk]=f2bf(vg-bf2f(hg));
  }
  __syncthreads();
  int c = w*16 + lr;
  f4_t xz0=(f4_t)(0.f), xr0=(f4_t)(0.f), xh0=(f4_t)(0.f);
  f4_t xz1=(f4_t)(0.f), xr1=(f4_t)(0.f), xh1=(f4_t)(0.f);
  f4_t hz0=(f4_t)(0.f), hr0=(f4_t)(0.f), hh0=(f4_t)(0.f);
  f4_t hz1=(f4_t)(0.f), hr1=(f4_t)(0.f), hh1=(f4_t)(0.f);
  #pragma unroll
  for (int kt=0; kt<4; kt++){
    int kof = kt*32 + lg*8;
    const bf8_t MA0h = *(const bf8_t*)&MsH[lr][kof];
    const bf8_t MA0l = *(const bf8_t*)&MsL[lr][kof];
    const bf8_t MA1h = *(const bf8_t*)&MsH[16+lr][kof];
    const bf8_t MA1l = *(const bf8_t*)&MsL[16+lr][kof];
    const bf8_t GA0h = *(const bf8_t*)&GsH[lr][kof];
    const bf8_t GA0l = *(const bf8_t*)&GsL[lr][kof];
    const bf8_t GA1h = *(const bf8_t*)&GsH[16+lr][kof];
    const bf8_t GA1l = *(const bf8_t*)&GsL[16+lr][kof];
    const bf8_t Wzh = *(const bf8_t*)(WnH + ((size_t)(      c))*128 + kof);
    const bf8_t Wzl = *(const bf8_t*)(WnL + ((size_t)(      c))*128 + kof);
    const bf8_t Wrh = *(const bf8_t*)(WnH + ((size_t)(128 + c))*128 + kof);
    const bf8_t Wrl = *(const bf8_t*)(WnL + ((size_t)(128 + c))*128 + kof);
    const bf8_t Whh = *(const bf8_t*)(WnH + ((size_t)(256 + c))*128 + kof);
    const bf8_t Whl = *(const bf8_t*)(WnL + ((size_t)(256 + c))*128 + kof);
    const bf8_t Uzh = *(const bf8_t*)(UnH + ((size_t)(      c))*128 + kof);
    const bf8_t Uzl = *(const bf8_t*)(UnL + ((size_t)(      c))*128 + kof);
    const bf8_t Urh = *(const bf8_t*)(UnH + ((size_t)(128 + c))*128 + kof);
    const bf8_t Url = *(const bf8_t*)(UnL + ((size_t)(128 + c))*128 + kof);
    const bf8_t Uhh = *(const bf8_t*)(UnH + ((size_t)(256 + c))*128 + kof);
    const bf8_t Uhl = *(const bf8_t*)(UnL + ((size_t)(256 + c))*128 + kof);
    xz0 = __builtin_amdgcn_mfma_f32_16x16x32_bf16(MA0h,Wzh,xz0,0,0,0);
    xz0 = __builtin_amdgcn_mfma_f32_16x16x32_bf16(MA0l,Wzh,xz0,0,0,0);
    xz0 = __builtin_amdgcn_mfma_f32_16x16x32_bf16(MA0h,Wzl,xz0,0,0,0);
    xz1 = __builtin_amdgcn_mfma_f32_16x16x32_bf16(MA1h,Wzh,xz1,0,0,0);
    xz1 = __builtin_amdgcn_mfma_f32_16x16x32_bf16(MA1l,Wzh,xz1,0,0,0);
    xz1 = __builtin_amdgcn_mfma_f32_16x16x32_bf16(MA1h,Wzl,xz1,0,0,0);
    xr0 = __builtin_amdgcn_mfma_f32_16x16x32_bf16(MA0h,Wrh,xr0,0,0,0);
    xr0 = __builtin_amdgcn_mfma_f32_16x16x32_bf16(MA0l,Wrh,xr0,0,0,0);
    xr0 = __builtin_amdgcn_mfma_f32_16x16x32_bf16(MA0h,Wrl,xr0,0,0,0);
    xr1 = __builtin_amdgcn_mfma_f32_16x16x32_bf16(MA1h,Wrh,xr1,0,0,0);
    xr1 = __builtin_amdgcn_mfma_f32_16x16x32_bf16(MA1l,Wrh,xr1,0,0,0);
    xr1 = __builtin_amdgcn_mfma_f32_16x16x32_bf16(MA1h,Wrl,xr1,0,0,0);
    xh0 = __builtin_amdgcn_mfma_f32_16x16x32_bf16(MA0h,Whh,xh0,0,0,0);
    xh0 = __builtin_amdgcn_mfma_f32_16x16x32_bf16(MA0l,Whh,xh0,0,0,0);
    xh0 = __builtin_amdgcn_mfma_f32_16x16x32_bf16(MA0h,Whl,xh0,0,0,0);
    xh1 = __builtin_amdgcn_mfma_f32_16x16x32_bf16(MA1h,Whh,xh1,0,0,0);
    xh1 = __builtin_amdgcn_mfma_f32_16x16x32_bf16(MA1l,Whh,xh1,0,0,0);
    xh1 = __builtin_amdgcn_mfma_f32_16x16x32_bf16(MA1h,Whl,xh1,0,0,0);
    hz0 = __builtin_amdgcn_mfma_f32_16x16x32_bf16(GA0h,Uzh,hz0,0,0,0);
    hz0 = __builtin_amdgcn_mfma_f32_16x16x32_bf16(GA0l,Uzh,hz0,0,0,0);
    hz0 = __builtin_amdgcn_mfma_f32_16x16x32_bf16(GA0h,Uzl,hz0,0,0,0);
    hz1 = __builtin_amdgcn_mfma_f32_16x16x32_bf16(GA1h,Uzh,hz1,0,0,0);
    hz1 = __builtin_amdgcn_mfma_f32_16x16x32_bf16(GA1l,Uzh,hz1,0,0,0);
    hz1 = __builtin_amdgcn_mfma_f32_16x16x32_bf16(GA1h,Uzl,hz1,0,0,0);
    hr0 = __builtin_amdgcn_mfma_f32_16x16x32_bf16(GA0h,Urh,hr0,0,0,0);
    hr0 = __builtin_amdgcn_mfma_f32_16x16x32_bf16(GA0l,Urh,hr0,0,0,0);
    hr0 = __builtin_amdgcn_mfma_f32_16x16x32_bf16(GA0h,Url,hr0,0,0,0);
    hr1 = __builtin_amdgcn_mfma_f32_16x16x32_bf16(GA1h,Urh,hr1,0,0,0);
    hr1 = __builtin_amdgcn_mfma_f32_16x16x32_bf16(GA1l,Urh,hr1,0,0,0);
    hr1 = __builtin_amdgcn_mfma_f32_16x16x32_bf16(GA1h,Url,hr1,0,0,0);
    hh0 = __builtin_amdgcn_mfma_f32_16x16x32_bf16(GA0h,Uhh,hh0,0,0,0);
    hh0 = __builtin_amdgcn_mfma_f32_16x16x32_bf16(GA0l,Uhh,hh0,0,0,0);
    hh0 = __builtin_amdgcn_mfma_f32_16x16x32_bf16(GA0h,Uhl,hh0,0,0,0);
    hh1 = __builtin_amdgcn_mfma_f32_16x16x32_bf16(GA1h,Uhh,hh1,0,0,0);
    hh1 = __builtin_amdgcn_mfma_f32_16x16x32_bf16(GA1l,Uhh,hh1,0,0,0);
    hh1 = __builtin_amdgcn_mfma_f32_16x16x32_bf16(GA1h,Uhl,hh1,0,0,0);
  }
  float bz = bn[c] + bn[G3+c] + gbUn[c];
  float br = bn[128+c] + bn[G3+128+c] + gbUn[128+c];
  float bxh = bn[256+c], bhh = bn[G3+256+c] + gbUn[256+c];
  float gbc = gb[c];
  #pragma unroll
  for (int q=0;q<4;q++){
    {
      int n = lg*4+q;
      float hval = bf2f(GsH[n][c]) + bf2f(GsL[n][c]) + gbc;
      float z = sigf(xz0[q] + hz0[q] + bz);
      float r = sigf(xr0[q] + hr0[q] + br);
      float hc = tanh_fast(xh0[q] + bxh + r*(hh0[q] + bhh));
      ns[(size_t)(r0+n)*DD + c] = z*hval + (1.f-z)*hc;
    }
    {
      int n = 16+lg*4+q;
      float hval = bf2f(GsH[n][c]) + bf2f(GsL[n][c]) + gbc;
      float z = sigf(xz1[q] + hz1[q] + bz);
      float r = sigf(xr1[q] + hr1[q] + br);
      float hc = tanh_fast(xh1[q] + bxh + r*(hh1[q] + bhh));
      ns[(size_t)(r0+n)*DD + c] = z*hval + (1.f-z)*hc;
    }
  }
}

/* ---------------- MFMA readout ---------------- */
__global__ __launch_bounds__(512) void k_read2(
    const float* __restrict__ ps,
    const ushort_t* __restrict__ r1h, const ushort_t* __restrict__ r1l,
    const ushort_t* __restrict__ r2h, const ushort_t* __restrict__ r2l,
    const float* __restrict__ rb1, const float* __restrict__ rb2,
    const float* __restrict__ rW3, const float* __restrict__ rb3,
    float* __restrict__ out)
{
  __shared__ __align__(16) ushort_t XsH[32][136], XsL[32][136];
  __shared__ __align__(16) char buf[32*264*2*2];
  ushort_t (*H1H)[264] = (ushort_t(*)[264])buf;
  ushort_t (*H1L)[264] = (ushort_t(*)[264])(buf + 32*264*2);
  float (*H2)[257] = (float(*)[257])buf;
  int pb = blockIdx.x*32, tid = threadIdx.x;
  int w = tid>>6, l = tid&63, lr = l&15, lg = l>>4;
  for (int idx=tid; idx<32*128; idx+=512){
    int pp=idx>>7, kk=idx&127;
    float v = ps[(size_t)(pb+pp)*DD+kk];
    ushort_t hi=f2bf(v); XsH[pp][kk]=hi; XsL[pp][kk]=f2bf(v-bf2f(hi));
  }
  __syncthreads();
  int col0 = w*32 + lr, col1 = col0 + 16;
  f4_t a00=(f4_t)(0.f), a01=(f4_t)(0.f), a10=(f4_t)(0.f), a11=(f4_t)(0.f);
  #pragma unroll
  for (int kt=0; kt<4; kt++){
    int kof = kt*32 + lg*8;
    const bf8_t Ah0 = *(const bf8_t*)&XsH[lr][kof];
    const bf8_t Al0 = *(const bf8_t*)&XsL[lr][kof];
    const bf8_t Ah1 = *(const bf8_t*)&XsH[16+lr][kof];
    const bf8_t Al1 = *(const bf8_t*)&XsL[16+lr][kof];
    const bf8_t B0h = *(const bf8_t*)(r1h + (size_t)col0*128 + kof);
    const bf8_t B0l = *(const bf8_t*)(r1l + (size_t)col0*128 + kof);
    const bf8_t B1h = *(const bf8_t*)(r1h + (size_t)col1*128 + kof);
    const bf8_t B1l = *(const bf8_t*)(r1l + (size_t)col1*128 + kof);
    a00 = __builtin_amdgcn_mfma_f32_16x16x32_bf16(Ah0,B0h,a00,0,0,0);
    a00 = __builtin_amdgcn_mfma_f32_16x16x32_bf16(Al0,B0h,a00,0,0,0);
    a00 = __builtin_amdgcn_mfma_f32_16x16x32_bf16(Ah0,B0l,a00,0,0,0);
    a01 = __builtin_amdgcn_mfma_f32_16x16x32_bf16(Ah0,B1h,a01,0,0,0);
    a01 = __builtin_amdgcn_mfma_f32_16x16x32_bf16(Al0,B1h,a01,0,0,0);
    a01 = __builtin_amdgcn_mfma_f32_16x16x32_bf16(Ah0,B1l,a01,0,0,0);
    a10 = __builtin_amdgcn_mfma_f32_16x16x32_bf16(Ah1,B0h,a10,0,0,0);
    a10 = __builtin_amdgcn_mfma_f32_16x16x32_bf16(Al1,B0h,a10,0,0,0);
    a10 = __builtin_amdgcn_mfma_f32_16x16x32_bf16(Ah1,B0l,a10,0,0,0);
    a11 = __builtin_amdgcn_mfma_f32_16x16x32_bf16(Ah1,B1h,a11,0,0,0);
    a11 = __builtin_amdgcn_mfma_f32_16x16x32_bf16(Al1,B1h,a11,0,0,0);
    a11 = __builtin_amdgcn_mfma_f32_16x16x32_bf16(Ah1,B1l,a11,0,0,0);
  }
  float rb1c0 = rb1[col0], rb1c1 = rb1[col1];
  #pragma unroll
  for (int q=0;q<4;q++){
    int row0 = lg*4+q, row1 = 16+lg*4+q;
    float v00 = a00[q]+rb1c0, v01 = a01[q]+rb1c1, v10 = a10[q]+rb1c0, v11 = a11[q]+rb1c1;
    v00 = 1.0507009873554805f * (v00>0.f ? v00 : 1.6732632423543772f*(__expf(v00)-1.f));
    v01 = 1.0507009873554805f * (v01>0.f ? v01 : 1.6732632423543772f*(__expf(v01)-1.f));
    v10 = 1.0507009873554805f * (v10>0.f ? v10 : 1.6732632423543772f*(__expf(v10)-1.f));
    v11 = 1.0507009873554805f * (v11>0.f ? v11 : 1.6732632423543772f*(__expf(v11)-1.f));
    ushort_t h;
    h=f2bf(v00); H1H[row0][col0]=h; H1L[row0][col0]=f2bf(v00-bf2f(h));
    h=f2bf(v01); H1H[row0][col1]=h; H1L[row0][col1]=f2bf(v01-bf2f(h));
    h=f2bf(v10); H1H[row1][col0]=h; H1L[row1][col0]=f2bf(v10-bf2f(h));
    h=f2bf(v11); H1H[row1][col1]=h; H1L[row1][col1]=f2bf(v11-bf2f(h));
  }
  __syncthreads();
  f4_t c00=(f4_t)(0.f), c01=(f4_t)(0.f), c10=(f4_t)(0.f), c11=(f4_t)(0.f);
  #pragma unroll
  for (int kt=0; kt<8; kt++){
    int kof = kt*32 + lg*8;
    const bf8_t Ah0 = *(const bf8_t*)&H1H[lr][kof];
    const bf8_t Al0 = *(const bf8_t*)&H1L[lr][kof];
    const bf8_t Ah1 = *(const bf8_t*)&H1H[16+lr][kof];
    const bf8_t Al1 = *(const bf8_t*)&H1L[16+lr][kof];
    const bf8_t B0h = *(const bf8_t*)(r2h + (size_t)col0*256 + kof);
    const bf8_t B0l = *(const bf8_t*)(r2l + (size_t)col0*256 + kof);
    const bf8_t B1h = *(const bf8_t*)(r2h + (size_t)col1*256 + kof);
    const bf8_t B1l = *(const bf8_t*)(r2l + (size_t)col1*256 + kof);
    c00 = __builtin_amdgcn_mfma_f32_16x16x32_bf16(Ah0,B0h,c00,0,0,0);
    c00 = __builtin_amdgcn_mfma_f32_16x16x32_bf16(Al0,B0h,c00,0,0,0);
    c00 = __builtin_amdgcn_mfma_f32_16x16x32_bf16(Ah0,B0l,c00,0,0,0);
    c01 = __builtin_amdgcn_mfma_f32_16x16x32_bf16(Ah0,B1h,c01,0,0,0);
    c01 = __builtin_amdgcn_mfma_f32_16x16x32_bf16(Al0,B1h,c01,0,0,0);
    c01 = __builtin_amdgcn_mfma_f32_16x16x32_bf16(Ah0,B1l,c01,0,0,0);
    c10 = __builtin_amdgcn_mfma_f32_16x16x32_bf16(Ah1,B0h,c10,0,0,0);
    c10 = __builtin_amdgcn_mfma_f32_16x16x32_bf16(Al1,B0h,c10,0,0,0);
    c10 = __builtin_amdgcn_mfma_f32_16x16x32_bf16(Ah1,B0l,c10,0,0,0);
    c11 = __builtin_amdgcn_mfma_f32_16x16x32_bf16(Ah1,B1h,c11,0,0,0);
    c11 = __builtin_amdgcn_mfma_f32_16x16x32_bf16(Al1,B1h,c11,0,0,0);
    c11 = __builtin_amdgcn_mfma_f32_16x16x32_bf16(Ah1,B1l,c11,0,0,0);
  }
  __syncthreads();
  float rb2c0 = rb2[col0], rb2c1 = rb2[col1];
  #pragma unroll
  for (int q=0;q<4;q++){
    int row0 = lg*4+q, row1 = 16+lg*4+q;
    H2[row0][col0] = fmaxf(c00[q]+rb2c0, 0.f);
    H2[row0][col1] = fmaxf(c01[q]+rb2c1, 0.f);
    H2[row1][col0] = fmaxf(c10[q]+rb2c0, 0.f);
    H2[row1][col1] = fmaxf(c11[q]+rb2c1, 0.f);
  }
  __syncthreads();
  int r = tid>>4, j0 = tid&15;
  float s = 0.f;
  for (int j=j0; j<256; j+=16) s += H2[r][j]*rW3[j];
  for (int o=8;o>0;o>>=1) s += __shfl_xor(s,o);
  if (j0==0) out[pb+r] = s + rb3[0];
}

/* ---------------- host ---------------- */
extern "C" void kernel_launch(void* const* d_in, const int* in_sizes, int n_in,
                              void* d_out, int out_size, void* d_ws, size_t ws_size,
                              hipStream_t stream)
{
  const float* ToS   = (const float*)d_in[0];
  const float* bw    = (const float*)d_in[1];
  const float* qpol  = (const float*)d_in[2];
  const float* w1    = (const float*)d_in[3];
  const float* w2    = (const float*)d_in[4];
  const float* w3    = (const float*)d_in[5];
  const float* qs    = (const float*)d_in[6];
  const float* lc    = (const float*)d_in[7];
  const float* gat_W = (const float*)d_in[8];
  const float* gat_as= (const float*)d_in[9];
  const float* gat_an= (const float*)d_in[10];
  const float* gat_b = (const float*)d_in[11];
  const float* Wp    = (const float*)d_in[12];
  const float* Up    = (const float*)d_in[13];
  const float* bp    = (const float*)d_in[14];
  const float* Wb    = (const float*)d_in[15];
  const float* Ub    = (const float*)d_in[16];
  const float* bb    = (const float*)d_in[17];
  const float* Wn    = (const float*)d_in[18];
  const float* Un    = (const float*)d_in[19];
  const float* bn    = (const float*)d_in[20];
  const float* rW1   = (const float*)d_in[21];
  const float* rb1   = (const float*)d_in[22];
  const float* rW2   = (const float*)d_in[23];
  const float* rb2   = (const float*)d_in[24];
  const float* rW3   = (const float*)d_in[25];
  const float* rb3   = (const float*)d_in[26];
  const int* paths   = (const int*)d_in[27];
  const int* seqs    = (const int*)d_in[28];
  const int* nodes   = (const int*)d_in[29];
  const int* adj_idx = (const int*)d_in[30];
  int E = in_sizes[27];

  char* w0 = (char*)d_ws;
  char* w = w0;
  auto alloc = [&](size_t nbytes)->void*{ void* r=(void*)w; w += (nbytes + 255) & ~(size_t)255; return r; };
  float* ns     = (float*)alloc((size_t)NN*DD*4);
  float* gout   = (float*)alloc((size_t)NN*DD*4);
  float* psA    = (float*)alloc((size_t)NP*DD*4);
  float* psB    = (float*)alloc((size_t)NP*DD*4);
  ushort_t* xpTh= (ushort_t*)alloc((size_t)NHD*NN*2);
  ushort_t* xpTl= (ushort_t*)alloc((size_t)NHD*NN*2);
  float* es     = (float*)alloc((size_t)NN*NH*4);
  float* en     = (float*)alloc((size_t)NN*NH*4);
  unsigned int* adjb = (unsigned int*)alloc((size_t)NN*16*4);
  float* xgp    = (float*)alloc((size_t)NN*G3*4);
  float* xgb    = (float*)alloc((size_t)NN*G3*4);
  float* m2     = (float*)alloc((size_t)NN*DD*4);
  float* bxgF   = (float*)alloc((size_t)G3*4);
  float* bxgB   = (float*)alloc((size_t)G3*4);
  float* gbUn   = (float*)alloc((size_t)G3*4);
  ushort_t* Uthp = (ushort_t*)alloc((size_t)G3*DD*2);
  ushort_t* Utlp = (ushort_t*)alloc((size_t)G3*DD*2);
  ushort_t* Uthb = (ushort_t*)alloc((size_t)G3*DD*2);
  ushort_t* Utlb = (ushort_t*)alloc((size_t)G3*DD*2);
  ushort_t* Wpth = (ushort_t*)alloc((size_t)G3*DD*2);
  ushort_t* Wptl = (ushort_t*)alloc((size_t)G3*DD*2);
  ushort_t* Wbth = (ushort_t*)alloc((size_t)G3*DD*2);
  ushort_t* Wbtl = (ushort_t*)alloc((size_t)G3*DD*2);
  ushort_t* WnTh = (ushort_t*)alloc((size_t)G3*DD*2);
  ushort_t* WnTl = (ushort_t*)alloc((size_t)G3*DD*2);
  ushort_t* UnTh = (ushort_t*)alloc((size_t)G3*DD*2);
  ushort_t* UnTl = (ushort_t*)alloc((size_t)G3*DD*2);
  ushort_t* r1h = (ushort_t*)alloc((size_t)256*128*2);
  ushort_t* r1l = (ushort_t*)alloc((size_t)256*128*2);
  ushort_t* r2h = (ushort_t*)alloc((size_t)256*256*2);
  ushort_t* r2l = (ushort_t*)alloc((size_t)256*256*2);
  ushort_t* gwh = (ushort_t*)alloc((size_t)NHD*DD*2);
  ushort_t* gwl = (ushort_t*)alloc((size_t)NHD*DD*2);
  int* start    = (int*)alloc((size_t)NP*4);
  int* lens     = (int*)alloc((size_t)NP*4);
  int* perm     = (int*)alloc((size_t)NP*4);
  int* lcnt     = (int*)alloc(16*4);
  int* loff     = (int*)alloc(16*4);
  int* lcur     = (int*)alloc(16*4);
  (void)n_in; (void)out_size; (void)ws_size;

  hipMemsetAsync(adjb, 0, (size_t)NN*16*4, stream);
  hipMemsetAsync(lcnt, 0, 16*4, stream);
  k_init_ns<<<NN,DD,0,stream>>>(ns, qpol, w1, w2, w3, qs);
  k_init_ps<<<(NP*DD+255)/256,256,0,stream>>>(psA, bw, ToS);
  k_adj<<<16,256,0,stream>>>(adjb, adj_idx, lc);
  k_meta<<<(E+255)/256,256,0,stream>>>(paths, seqs, start, lens, E);
  k_lcount<<<(NP+255)/256,256,0,stream>>>(lens, lcnt);
  k_lscan<<<1,64,0,stream>>>(lcnt, loff, lcur);
  k_lfill<<<(NP+255)/256,256,0,stream>>>(lens, lcur, perm);
  k_wsplit6<<<(6*G3*DD+255)/256,256,0,stream>>>(Up, Ub, Wp, Wb, Wn, Un,
      Uthp,Utlp, Uthb,Utlb, Wpth,Wptl, Wbth,Wbtl, WnTh,WnTl, UnTh,UnTl);
  k_wsplit<<<(256*128+255)/256,256,0,stream>>>(rW1, r1h, r1l, 7, 256, 256*128);
  k_wsplit<<<(256*256+255)/256,256,0,stream>>>(rW2, r2h, r2l, 8, 256, 256*256);
  k_wsplit<<<(NHD*DD+255)/256,256,0,stream>>>(gat_W, gwh, gwl, 7, NHD, NHD*DD);
  k_gbw<<<3,G3,0,stream>>>(gat_b, Wp, Wb, Un, bp, bb, bxgF, bxgB, gbUn);

  float* ps_cur = psA; float* ps_nxt = psB;
  for (int t=0;t<3;t++){
    hipMemsetAsync(gout, 0, (size_t)NN*DD*4, stream);
    k_xp2<<<dim3(NN/32, NHD/256),512,0,stream>>>(ns, gwh, gwl, gat_as, gat_an, xpTh, xpTl, es, en);
    k_attn2<<<dim3(NH, NN/32),256,0,stream>>>(xpTh, xpTl, es, en, adjb, gout);
    k_xg3<<<dim3(NN/32,6),512,0,stream>>>(gout, Wpth, Wptl, Wbth, Wbtl, bxgF, bxgB, xgp, xgb);
    hipMemsetAsync(m2, 0, (size_t)NN*DD*4, stream);
    k_gru2<<<2*(NP/32),512,0,stream>>>(ps_cur, ps_nxt, xgp, xgb, Uthp, Utlp, Uthb, Utlb,
                                       bp+G3, bb+G3, start, lens, nodes, perm, m2);
    k_ngru3<<<NN/32,512,0,stream>>>(m2, gout, WnTh, WnTl, UnTh, UnTl, bn, gat_b, gbUn, ns);
    float* tmp = ps_cur; ps_cur = ps_nxt; ps_nxt = tmp;
  }
  k_read2<<<NP/32,512,0,stream>>>(ps_cur, r1h, r1l, r2h, r2l, rb1, rb2, rW3, rb3, (float*)d_out);
}

// Round 12
// 1029.872 us; speedup vs baseline: 1.4775x; 1.0265x over previous
//
#include <hip/hip_runtime.h>
#include <math.h>

#define NN 512
#define NP 20000
#define DD 128
#define NH 24
#define G3 384
#define NHD 3072  /* NH*DD */

typedef __attribute__((ext_vector_type(8))) short bf8_t;   /* 8 bf16 */
typedef __attribute__((ext_vector_type(4))) float f4_t;
typedef unsigned short ushort_t;

/* fast transcendentals */
__device__ __forceinline__ float sigf(float x){
  return __builtin_amdgcn_rcpf(1.f + __expf(-x));
}
__device__ __forceinline__ float tanh_fast(float x){
  float ax = fabsf(x);
  float e = __expf(-2.f*ax);
  float t = (1.f - e) * __builtin_amdgcn_rcpf(1.f + e);
  return copysignf(t, x);
}
__device__ __forceinline__ unsigned short f2bf(float f){
  unsigned int u = __float_as_uint(f);
  unsigned int r = (u + 0x7fffu + ((u>>16)&1u)) >> 16;
  return (unsigned short)r;
}
__device__ __forceinline__ float bf2f(unsigned short h){
  return __uint_as_float(((unsigned int)h)<<16);
}

/* ---------------- init ---------------- */
__global__ void k_init_ns(float* ns, const float* qp, const float* w1, const float* w2,
                          const float* w3, const float* qs){
  int n = blockIdx.x, c = threadIdx.x;
  float v = 0.f;
  if (c==0) v=qp[n]; else if (c==1) v=w1[n]; else if (c==2) v=w2[n]; else if (c==3) v=w3[n];
  else if (c<7) v=qs[n*3 + (c-4)];
  ns[n*DD+c]=v;
}

__global__ void k_init_ps(float* ps, const float* bw, const float* tos){
  int i = blockIdx.x*256 + threadIdx.x;
  if (i >= NP*DD) return;
  int p = i>>7, c = i&127;
  float v=0.f; if(c==0) v=bw[p]; else if(c==1) v=tos[p];
  ps[i]=v;
}

/* adjacency as bitmask */
__global__ void k_adj(unsigned int* adjb, const int* idx, const float* lc){
  int l = blockIdx.x*256+threadIdx.x; if(l>=4096) return;
  if (lc[l]!=0.f){
    int a = idx[l]; int i = a>>9, j = a&511;
    atomicOr(&adjb[i*16 + (j>>5)], 1u<<(j&31));
  }
}

__global__ void k_meta(const int* paths, const int* seqs, int* start, int* lens, int E){
  int e = blockIdx.x*256+threadIdx.x; if(e>=E) return;
  int p=paths[e], s=seqs[e];
  if (s==0) start[p]=e;
  if (e==E-1 || paths[e+1]!=p) lens[p]=s+1;
}

/* ---- length sort (counting sort, descending) ---- */
__global__ void k_lcount(const int* __restrict__ lens, int* lcnt){
  int p = blockIdx.x*256+threadIdx.x; if(p>=NP) return;
  atomicAdd(&lcnt[lens[p]],1);
}
__global__ void k_lscan(const int* __restrict__ lcnt, int* loff, int* lcur){
  if (threadIdx.x==0){
    int acc=0;
    for (int L=15; L>=0; --L){ loff[L]=acc; lcur[L]=acc; acc+=lcnt[L]; }
  }
}
__global__ void k_lfill(const int* __restrict__ lens, int* lcur, int* perm){
  int p = blockIdx.x*256+threadIdx.x; if(p>=NP) return;
  int pos = atomicAdd(&lcur[lens[p]],1);
  perm[pos]=p;
}

/* transpose+split: W [K][ncols] -> Wt hi/lo [ncols][K], K = 1<<shift */
__global__ void k_wsplit(const float* __restrict__ W, ushort_t* __restrict__ Wh,
                         ushort_t* __restrict__ Wl, int shift, int ncols, int total){
  int i = blockIdx.x*256 + threadIdx.x;
  if (i >= total) return;
  int col = i >> shift, k = i & ((1<<shift)-1);
  float v = W[(size_t)k*ncols + col];
  ushort_t h = f2bf(v);
  Wh[i] = h; Wl[i] = f2bf(v - bf2f(h));
}

/* batch split for the six G3xDD matrices */
__global__ void k_wsplit6(
    const float* S0,const float* S1,const float* S2,const float* S3,const float* S4,const float* S5,
    ushort_t* H0, ushort_t* L0, ushort_t* H1, ushort_t* L1, ushort_t* H2, ushort_t* L2,
    ushort_t* H3, ushort_t* L3, ushort_t* H4, ushort_t* L4, ushort_t* H5, ushort_t* L5){
  int i = blockIdx.x*256 + threadIdx.x;
  if (i >= 6*G3*DD) return;
  int m = i/(G3*DD), r = i - m*(G3*DD);
  const float* S = m==0?S0:m==1?S1:m==2?S2:m==3?S3:m==4?S4:S5;
  ushort_t* Hh = m==0?H0:m==1?H1:m==2?H2:m==3?H3:m==4?H4:H5;
  ushort_t* Ll = m==0?L0:m==1?L1:m==2?L2:m==3?L3:m==4?L4:L5;
  int col = r>>7, k = r&127;
  float v = S[(size_t)k*G3 + col];
  ushort_t h = f2bf(v);
  Hh[r] = h; Ll[r] = f2bf(v - bf2f(h));
}

/* bias folds: bxgF = bp + gb@Wp ; bxgB = bb + gb@Wb ; gbUn = gb@Un */
__global__ void k_gbw(const float* __restrict__ gb,
                      const float* __restrict__ Wp, const float* __restrict__ Wb,
                      const float* __restrict__ Un,
                      const float* __restrict__ bp, const float* __restrict__ bb,
                      float* bxgF, float* bxgB, float* gbUn){
  int m = blockIdx.x; int j = threadIdx.x; /* 384 threads */
  const float* W = m==0?Wp:(m==1?Wb:Un);
  float a = m==0?bp[j]:(m==1?bb[j]:0.f);
  for (int k=0;k<128;k++) a += gb[k]*W[(size_t)k*G3+j];
  (m==0?bxgF:(m==1?bxgB:gbUn))[j]=a;
}

/* ---------------- GAT: xp GEMM -> xpT (bf16 split, [col][node]) + fused es/en ----------------
   y==0 blocks also zero gout (consumed by k_attn2 atomics, which runs after). */
__global__ __launch_bounds__(512) void k_xp2(const float* __restrict__ ns,
                      const ushort_t* __restrict__ gwh, const ushort_t* __restrict__ gwl,
                      const float* __restrict__ as_, const float* __restrict__ an_,
                      ushort_t* __restrict__ xpTh, ushort_t* __restrict__ xpTl,
                      float* __restrict__ es, float* __restrict__ en,
                      float* __restrict__ gout){
  __shared__ __align__(16) ushort_t XsH[32][136], XsL[32][136];
  __shared__ float ered[8][32][2];   /* [wave][row][es/en] partials */
  int r0 = blockIdx.x*32, c0 = blockIdx.y*256;
  int tid = threadIdx.x;
  int w = tid>>6, l = tid&63, lr = l&15, lg = l>>4;
  if (blockIdx.y==0){
    for (int idx=tid; idx<32*128; idx+=512){
      int pp=idx>>7, kk=idx&127;
      gout[(size_t)(r0+pp)*DD+kk] = 0.f;
    }
  }
  for (int idx=tid; idx<32*128; idx+=512){
    int pp=idx>>7, kk=idx&127;
    float v = ns[(size_t)(r0+pp)*DD+kk];
    ushort_t hi=f2bf(v); XsH[pp][kk]=hi; XsL[pp][kk]=f2bf(v-bf2f(hi));
  }
  __syncthreads();
  int col0 = c0 + w*32 + lr, col1 = col0 + 16;
  f4_t a00=(f4_t)(0.f), a01=(f4_t)(0.f), a10=(f4_t)(0.f), a11=(f4_t)(0.f);
  #pragma unroll
  for (int kt=0; kt<4; kt++){
    int kof = kt*32 + lg*8;
    const bf8_t Ah0 = *(const bf8_t*)&XsH[lr][kof];
    const bf8_t Al0 = *(const bf8_t*)&XsL[lr][kof];
    const bf8_t Ah1 = *(const bf8_t*)&XsH[16+lr][kof];
    const bf8_t Al1 = *(const bf8_t*)&XsL[16+lr][kof];
    const bf8_t B0h = *(const bf8_t*)(gwh + (size_t)col0*128 + kof);
    const bf8_t B0l = *(const bf8_t*)(gwl + (size_t)col0*128 + kof);
    const bf8_t B1h = *(const bf8_t*)(gwh + (size_t)col1*128 + kof);
    const bf8_t B1l = *(const bf8_t*)(gwl + (size_t)col1*128 + kof);
    a00 = __builtin_amdgcn_mfma_f32_16x16x32_bf16(Ah0,B0h,a00,0,0,0);
    a00 = __builtin_amdgcn_mfma_f32_16x16x32_bf16(Al0,B0h,a00,0,0,0);
    a00 = __builtin_amdgcn_mfma_f32_16x16x32_bf16(Ah0,B0l,a00,0,0,0);
    a01 = __builtin_amdgcn_mfma_f32_16x16x32_bf16(Ah0,B1h,a01,0,0,0);
    a01 = __builtin_amdgcn_mfma_f32_16x16x32_bf16(Al0,B1h,a01,0,0,0);
    a01 = __builtin_amdgcn_mfma_f32_16x16x32_bf16(Ah0,B1l,a01,0,0,0);
    a10 = __builtin_amdgcn_mfma_f32_16x16x32_bf16(Ah1,B0h,a10,0,0,0);
    a10 = __builtin_amdgcn_mfma_f32_16x16x32_bf16(Al1,B0h,a10,0,0,0);
    a10 = __builtin_amdgcn_mfma_f32_16x16x32_bf16(Ah1,B0l,a10,0,0,0);
    a11 = __builtin_amdgcn_mfma_f32_16x16x32_bf16(Ah1,B1h,a11,0,0,0);
    a11 = __builtin_amdgcn_mfma_f32_16x16x32_bf16(Al1,B1h,a11,0,0,0);
    a11 = __builtin_amdgcn_mfma_f32_16x16x32_bf16(Ah1,B1l,a11,0,0,0);
  }
  /* store transposed split-bf16: xpT[col][node]; 4 consecutive nodes packed */
  {
    ushort4 h00,l00,h01,l01,h10,l10,h11,l11;
    #pragma unroll
    for (int q=0;q<4;q++){
      float v; ushort_t hh;
      v=a00[q]; hh=f2bf(v); ((ushort_t*)&h00)[q]=hh; ((ushort_t*)&l00)[q]=f2bf(v-bf2f(hh));
      v=a01[q]; hh=f2bf(v); ((ushort_t*)&h01)[q]=hh; ((ushort_t*)&l01)[q]=f2bf(v-bf2f(hh));
      v=a10[q]; hh=f2bf(v); ((ushort_t*)&h10)[q]=hh; ((ushort_t*)&l10)[q]=f2bf(v-bf2f(hh));
      v=a11[q]; hh=f2bf(v); ((ushort_t*)&h11)[q]=hh; ((ushort_t*)&l11)[q]=f2bf(v-bf2f(hh));
    }
    size_t b0 = (size_t)col0*NN + r0 + lg*4;
    size_t b1 = (size_t)col1*NN + r0 + lg*4;
    *(ushort4*)(xpTh + b0)      = h00; *(ushort4*)(xpTl + b0)      = l00;
    *(ushort4*)(xpTh + b1)      = h01; *(ushort4*)(xpTl + b1)      = l01;
    *(ushort4*)(xpTh + b0 + 16) = h10; *(ushort4*)(xpTl + b0 + 16) = l10;
    *(ushort4*)(xpTh + b1 + 16) = h11; *(ushort4*)(xpTl + b1 + 16) = l11;
  }
  /* es/en partials: wave w covers one head hw, cols [w*32, w*32+32) */
  {
    int hw = blockIdx.y*2 + (w>>2);
    int cc0 = (w*32 + lr)&127, cc1 = (w*32 + 16 + lr)&127;
    float as0 = as_[hw*DD+cc0], as1 = as_[hw*DD+cc1];
    float an0 = an_[hw*DD+cc0], an1 = an_[hw*DD+cc1];
    #pragma unroll
    for (int q=0;q<4;q++){
      float s0 = a00[q]*as0 + a01[q]*as1;
      float n0 = a00[q]*an0 + a01[q]*an1;
      float s1 = a10[q]*as0 + a11[q]*as1;
      float n1 = a10[q]*an0 + a11[q]*an1;
      #pragma unroll
      for (int o=1;o<16;o<<=1){
        s0 += __shfl_xor(s0,o); n0 += __shfl_xor(n0,o);
        s1 += __shfl_xor(s1,o); n1 += __shfl_xor(n1,o);
      }
      if (lr==0){
        ered[w][lg*4+q][0]=s0;    ered[w][lg*4+q][1]=n0;
        ered[w][16+lg*4+q][0]=s1; ered[w][16+lg*4+q][1]=n1;
      }
    }
  }
  __syncthreads();
  if (tid < 128){
    int row = tid&31, hh = (tid>>5)&1, which = tid>>6;
    float v = ered[hh*4+0][row][which] + ered[hh*4+1][row][which]
            + ered[hh*4+2][row][which] + ered[hh*4+3][row][which];
    float* dst = which? en : es;
    dst[(size_t)(r0+row)*NH + blockIdx.y*2 + hh] = v;
  }
}

/* attn (512 thr): max pass + single-exp pass (unnormalized P), MFMA PV (8 waves),
   1/s folded in epilogue; atomics into gout (pre-zeroed by k_xp2) */
__global__ __launch_bounds__(512) void k_attn2(
    const ushort_t* __restrict__ xpTh, const ushort_t* __restrict__ xpTl,
    const float* __restrict__ es, const float* __restrict__ en,
    const unsigned int* __restrict__ adjb, float* __restrict__ gout)
{
  __shared__ __align__(16) ushort_t PsH[32][520], PsL[32][520];
  __shared__ float enl[512], esl[32];
  __shared__ unsigned int am[32][16];
  __shared__ float isms[32];
  int h = blockIdx.x, i0 = blockIdx.y*32, tid = threadIdx.x;
  for (int j=tid; j<512; j+=512) enl[j] = en[(size_t)j*NH + h];
  if (tid < 512 && tid >= 0){ /* am: 512 words */
    am[tid>>4][tid&15] = adjb[(i0+(tid>>4))*16 + (tid&15)];
  }
  if (tid<32) esl[tid] = es[(size_t)(i0+tid)*NH + h];
  __syncthreads();
  {
    int t16 = tid&15, ii = tid>>4;
    float esr = esl[ii];
    /* pass 1: max only */
    float m = -INFINITY;
    for (int j=t16; j<512; j+=16){
      float lv = esr + enl[j];
      lv = (lv>=0.f)? lv : 0.2f*lv;
      if (!((am[ii][j>>5]>>(j&31))&1u)) lv = -1000000000.0f;
      m = fmaxf(m, lv);
    }
    #pragma unroll
    for (int o=8;o>0;o>>=1) m = fmaxf(m, __shfl_xor(m,o));
    /* pass 2: single exp, store unnormalized split-bf16 P, register sum */
    float s = 0.f;
    for (int j=t16; j<512; j+=16){
      float lv = esr + enl[j];
      lv = (lv>=0.f)? lv : 0.2f*lv;
      if (!((am[ii][j>>5]>>(j&31))&1u)) lv = -1000000000.0f;
      float e = __expf(lv - m);
      s += e;
      ushort_t hi = f2bf(e);
      PsH[ii][j] = hi; PsL[ii][j] = f2bf(e - bf2f(hi));
    }
    #pragma unroll
    for (int o=8;o>0;o>>=1) s += __shfl_xor(s,o);
    if (t16==0) isms[ii] = __builtin_amdgcn_rcpf(s);
  }
  __syncthreads();
  /* PV via MFMA: P(32x512) @ xpT_h(512x128); wave wv owns cols [wv*16, wv*16+16) */
  int wv = tid>>6, ln = tid&63, lr = ln&15, lg = ln>>4;
  const ushort_t* Bhp = xpTh + ((size_t)(h*DD + wv*16 + lr))*NN;
  const ushort_t* Blp = xpTl + ((size_t)(h*DD + wv*16 + lr))*NN;
  f4_t a0=(f4_t)(0.f), a1=(f4_t)(0.f);
  #pragma unroll
  for (int kt=0; kt<16; kt++){
    int kof = kt*32 + lg*8;
    const bf8_t A0h = *(const bf8_t*)&PsH[lr][kof];
    const bf8_t A0l = *(const bf8_t*)&PsL[lr][kof];
    const bf8_t A1h = *(const bf8_t*)&PsH[16+lr][kof];
    const bf8_t A1l = *(const bf8_t*)&PsL[16+lr][kof];
    const bf8_t Bh = *(const bf8_t*)(Bhp + kof);
    const bf8_t Bl = *(const bf8_t*)(Blp + kof);
    a0 = __builtin_amdgcn_mfma_f32_16x16x32_bf16(A0h,Bh,a0,0,0,0);
    a0 = __builtin_amdgcn_mfma_f32_16x16x32_bf16(A0l,Bh,a0,0,0,0);
    a0 = __builtin_amdgcn_mfma_f32_16x16x32_bf16(A0h,Bl,a0,0,0,0);
    a1 = __builtin_amdgcn_mfma_f32_16x16x32_bf16(A1h,Bh,a1,0,0,0);
    a1 = __builtin_amdgcn_mfma_f32_16x16x32_bf16(A1l,Bh,a1,0,0,0);
    a1 = __builtin_amdgcn_mfma_f32_16x16x32_bf16(A1h,Bl,a1,0,0,0);
  }
  const float inv = 1.f/24.f;
  #pragma unroll
  for (int q=0;q<4;q++){
    int r0w = lg*4+q, r1w = 16+lg*4+q;
    float s0 = isms[r0w]*inv, s1 = isms[r1w]*inv;
    atomicAdd(&gout[(size_t)(i0+r0w)*DD + wv*16 + lr], a0[q]*s0);
    atomicAdd(&gout[(size_t)(i0+r1w)*DD + wv*16 + lr], a1[q]*s1);
  }
}

/* xg for both dirs via MFMA; bias vector includes gb@W fold.
   y==0 blocks also zero m2 (consumed by k_gru2 atomics, which runs after). */
__global__ __launch_bounds__(512) void k_xg3(const float* __restrict__ gout,
      const ushort_t* __restrict__ WpH, const ushort_t* __restrict__ WpL,
      const ushort_t* __restrict__ WbH, const ushort_t* __restrict__ WbL,
      const float* __restrict__ bxgF, const float* __restrict__ bxgB,
      float* __restrict__ xgF, float* __restrict__ xgB, float* __restrict__ m2){
  __shared__ __align__(16) ushort_t XsH[32][136], XsL[32][136];
  int r0 = blockIdx.x*32;
  int mat = blockIdx.y/3, cg = blockIdx.y%3;
  const ushort_t* Wh = mat? WbH : WpH;
  const ushort_t* Wl = mat? WbL : WpL;
  const float* b0 = mat? bxgB : bxgF;
  float* out = mat? xgB : xgF;
  int tid = threadIdx.x;
  int w = tid>>6, l = tid&63, lr = l&15, lg = l>>4;
  if (blockIdx.y==0){
    for (int idx=tid; idx<32*128; idx+=512){
      int pp=idx>>7, kk=idx&127;
      m2[(size_t)(r0+pp)*DD+kk] = 0.f;
    }
  }
  for (int idx=tid; idx<32*128; idx+=512){
    int pp=idx>>7, kk=idx&127;
    float v = gout[(size_t)(r0+pp)*DD+kk];
    ushort_t hi=f2bf(v); XsH[pp][kk]=hi; XsL[pp][kk]=f2bf(v-bf2f(hi));
  }
  __syncthreads();
  int col = cg*128 + w*16 + lr;
  f4_t a0=(f4_t)(0.f), a1=(f4_t)(0.f);
  #pragma unroll
  for (int kt=0; kt<4; kt++){
    int kof = kt*32 + lg*8;
    const bf8_t Ah0 = *(const bf8_t*)&XsH[lr][kof];
    const bf8_t Al0 = *(const bf8_t*)&XsL[lr][kof];
    const bf8_t Ah1 = *(const bf8_t*)&XsH[16+lr][kof];
    const bf8_t Al1 = *(const bf8_t*)&XsL[16+lr][kof];
    const bf8_t Bh = *(const bf8_t*)(Wh + (size_t)col*128 + kof);
    const bf8_t Bl = *(const bf8_t*)(Wl + (size_t)col*128 + kof);
    a0 = __builtin_amdgcn_mfma_f32_16x16x32_bf16(Ah0,Bh,a0,0,0,0);
    a0 = __builtin_amdgcn_mfma_f32_16x16x32_bf16(Al0,Bh,a0,0,0,0);
    a0 = __builtin_amdgcn_mfma_f32_16x16x32_bf16(Ah0,Bl,a0,0,0,0);
    a1 = __builtin_amdgcn_mfma_f32_16x16x32_bf16(Ah1,Bh,a1,0,0,0);
    a1 = __builtin_amdgcn_mfma_f32_16x16x32_bf16(Al1,Bh,a1,0,0,0);
    a1 = __builtin_amdgcn_mfma_f32_16x16x32_bf16(Ah1,Bl,a1,0,0,0);
  }
  float bb0 = b0[col];
  #pragma unroll
  for (int q=0;q<4;q++){
    out[(size_t)(r0+lg*4+q)*G3 + col]    = a0[q] + bb0;
    out[(size_t)(r0+16+lg*4+q)*G3 + col] = a1[q] + bb0;
  }
}

/* ---------------- fused bidirectional path GRU (split-bf16 MFMA, 32 paths) ---------------- */
__global__ __launch_bounds__(512) void k_gru2(
    const float* __restrict__ ps_in, float* __restrict__ ps_out,
    const float* __restrict__ xgF, const float* __restrict__ xgB,
    const ushort_t* __restrict__ UthF, const ushort_t* __restrict__ UtlF,
    const ushort_t* __restrict__ UthB, const ushort_t* __restrict__ UtlB,
    const float* __restrict__ b1F, const float* __restrict__ b1B,
    const int* __restrict__ start, const int* __restrict__ lens,
    const int* __restrict__ nodes, const int* __restrict__ perm,
    float* __restrict__ m2)
{
  __shared__ __align__(16) ushort_t HsH[2][32][136];
  __shared__ __align__(16) ushort_t HsL[2][32][136];
  __shared__ int Ls[32], Ss[32], Pid[32];
  __shared__ int nid_l[32][8];

  int dir = blockIdx.x & 1, pblk = blockIdx.x >> 1;
  const bool rev = (dir==1);
  const float* xg = rev ? xgB : xgF;
  const ushort_t* Uth = rev ? UthB : UthF;
  const ushort_t* Utl = rev ? UtlB : UtlF;
  const float* b1 = rev ? b1B : b1F;
  float* psn = rev ? (float*)0 : ps_out;

  int pb = pblk*32;
  int tid = threadIdx.x;
  int w = tid>>6, l = tid&63;
  int lr = l&15, lg = l>>4;
  int c = w*16 + lr;

  if (tid<32){ int pid = perm[pb+tid]; Pid[tid]=pid; Ls[tid]=lens[pid]; Ss[tid]=start[pid]; }
  __syncthreads();
  for (int idx=tid; idx<32*128; idx+=512){
    int pp=idx>>7, kk=idx&127;
    float v = ps_in[(size_t)Pid[pp]*DD+kk];
    ushort_t hi = f2bf(v);
    HsH[0][pp][kk]=hi; HsL[0][pp][kk]=f2bf(v - bf2f(hi));
  }
  if (tid<256){
    int p=tid>>3, s=tid&7; int L=Ls[p];
    int nid = 0;
    if (s<L){ int pos = rev ? (L-1-s) : s; nid = nodes[Ss[p]+pos]; }
    nid_l[p][s]=nid;
  }
  __syncthreads();

  int Lmax = Ls[0];
  int Lv[8];
  #pragma unroll
  for (int i=0;i<8;i++){ int p=(i>>2)*16 + lg*4 + (i&3); Lv[i]=Ls[p]; }
  float b1z = b1[c], b1r = b1[128+c], b1h = b1[256+c];

  int cur = 0;
  for (int s=0;s<Lmax;s++){
    int nxt = cur^1;
    bool act[8]; int niv[8]; float xzv[8], xrv[8], xhv[8];
    #pragma unroll
    for (int i=0;i<8;i++){
      int p=(i>>2)*16 + lg*4 + (i&3);
      act[i] = (s < Lv[i]);
      int nid = nid_l[p][s];
      niv[i] = nid;
      const float* xr = xg + (size_t)nid*G3;
      xzv[i]=xr[c]; xrv[i]=xr[128+c]; xhv[i]=xr[256+c];
    }
    f4_t accz0=(f4_t)(0.f), accz1=(f4_t)(0.f);
    f4_t accr0=(f4_t)(0.f), accr1=(f4_t)(0.f);
    f4_t acch0=(f4_t)(0.f), acch1=(f4_t)(0.f);
    #pragma unroll
    for (int kt=0; kt<4; kt++){
      int kof = kt*32 + lg*8;
      const bf8_t Ahi0 = *(const bf8_t*)&HsH[cur][lr][kof];
      const bf8_t Alo0 = *(const bf8_t*)&HsL[cur][lr][kof];
      const bf8_t Ahi1 = *(const bf8_t*)&HsH[cur][16+lr][kof];
      const bf8_t Alo1 = *(const bf8_t*)&HsL[cur][16+lr][kof];
      const bf8_t Bhz = *(const bf8_t*)(Uth + ((size_t)(      c))*128 + kof);
      const bf8_t Blz = *(const bf8_t*)(Utl + ((size_t)(      c))*128 + kof);
      const bf8_t Bhr = *(const bf8_t*)(Uth + ((size_t)(128 + c))*128 + kof);
      const bf8_t Blr = *(const bf8_t*)(Utl + ((size_t)(128 + c))*128 + kof);
      const bf8_t Bhh = *(const bf8_t*)(Uth + ((size_t)(256 + c))*128 + kof);
      const bf8_t Blh = *(const bf8_t*)(Utl + ((size_t)(256 + c))*128 + kof);
      accz0 = __builtin_amdgcn_mfma_f32_16x16x32_bf16(Ahi0, Bhz, accz0, 0,0,0);
      accz0 = __builtin_amdgcn_mfma_f32_16x16x32_bf16(Alo0, Bhz, accz0, 0,0,0);
      accz0 = __builtin_amdgcn_mfma_f32_16x16x32_bf16(Ahi0, Blz, accz0, 0,0,0);
      accz1 = __builtin_amdgcn_mfma_f32_16x16x32_bf16(Ahi1, Bhz, accz1, 0,0,0);
      accz1 = __builtin_amdgcn_mfma_f32_16x16x32_bf16(Alo1, Bhz, accz1, 0,0,0);
      accz1 = __builtin_amdgcn_mfma_f32_16x16x32_bf16(Ahi1, Blz, accz1, 0,0,0);
      accr0 = __builtin_amdgcn_mfma_f32_16x16x32_bf16(Ahi0, Bhr, accr0, 0,0,0);
      accr0 = __builtin_amdgcn_mfma_f32_16x16x32_bf16(Alo0, Bhr, accr0, 0,0,0);
      accr0 = __builtin_amdgcn_mfma_f32_16x16x32_bf16(Ahi0, Blr, accr0, 0,0,0);
      accr1 = __builtin_amdgcn_mfma_f32_16x16x32_bf16(Ahi1, Bhr, accr1, 0,0,0);
      accr1 = __builtin_amdgcn_mfma_f32_16x16x32_bf16(Alo1, Bhr, accr1, 0,0,0);
      accr1 = __builtin_amdgcn_mfma_f32_16x16x32_bf16(Ahi1, Blr, accr1, 0,0,0);
      acch0 = __builtin_amdgcn_mfma_f32_16x16x32_bf16(Ahi0, Bhh, acch0, 0,0,0);
      acch0 = __builtin_amdgcn_mfma_f32_16x16x32_bf16(Alo0, Bhh, acch0, 0,0,0);
      acch0 = __builtin_amdgcn_mfma_f32_16x16x32_bf16(Ahi0, Blh, acch0, 0,0,0);
      acch1 = __builtin_amdgcn_mfma_f32_16x16x32_bf16(Ahi1, Bhh, acch1, 0,0,0);
      acch1 = __builtin_amdgcn_mfma_f32_16x16x32_bf16(Alo1, Bhh, acch1, 0,0,0);
      acch1 = __builtin_amdgcn_mfma_f32_16x16x32_bf16(Ahi1, Blh, acch1, 0,0,0);
    }
#define EPI(i, mt, qq, AZ, AR, AH) { \
    int p = (mt)*16 + lg*4 + (qq); \
    if (act[i]) { \
      float hold = bf2f(HsH[cur][p][c]) + bf2f(HsL[cur][p][c]); \
      float z = sigf(xzv[i] + (AZ) + b1z); \
      float r = sigf(xrv[i] + (AR) + b1r); \
      float hc = tanh_fast(xhv[i] + r*((AH) + b1h)); \
      float hn = z*hold + (1.f-z)*hc; \
      ushort_t hi2 = f2bf(hn); \
      HsH[nxt][p][c]=hi2; HsL[nxt][p][c]=f2bf(hn - bf2f(hi2)); \
      atomicAdd(&m2[(size_t)niv[i]*DD + c], hn); \
    } else { \
      HsH[nxt][p][c]=HsH[cur][p][c]; HsL[nxt][p][c]=HsL[cur][p][c]; \
    } }
    EPI(0,0,0, accz0.x, accr0.x, acch0.x)
    EPI(1,0,1, accz0.y, accr0.y, acch0.y)
    EPI(2,0,2, accz0.z, accr0.z, acch0.z)
    EPI(3,0,3, accz0.w, accr0.w, acch0.w)
    EPI(4,1,0, accz1.x, accr1.x, acch1.x)
    EPI(5,1,1, accz1.y, accr1.y, acch1.y)
    EPI(6,1,2, accz1.z, accr1.z, acch1.z)
    EPI(7,1,3, accz1.w, accr1.w, acch1.w)
#undef EPI
    __syncthreads();
    cur = nxt;
  }
  if (psn){
    for (int idx=tid; idx<32*128; idx+=512){
      int pp=idx>>7, kk=idx&127;
      psn[(size_t)Pid[pp]*DD+kk] = bf2f(HsH[cur][pp][kk]) + bf2f(HsL[cur][pp][kk]);
    }
  }
}

/* ---------------- node GRU via MFMA (bias folds) ---------------- */
__global__ __launch_bounds__(512) void k_ngru3(
    const float* __restrict__ m2, const float* __restrict__ gout,
    const ushort_t* __restrict__ WnH, const ushort_t* __restrict__ WnL,
    const ushort_t* __restrict__ UnH, const ushort_t* __restrict__ UnL,
    const float* __restrict__ bn, const float* __restrict__ gb,
    const float* __restrict__ gbUn, float* __restrict__ ns)
{
  __shared__ __align__(16) ushort_t MsH[32][136], MsL[32][136];
  __shared__ __align__(16) ushort_t GsH[32][136], GsL[32][136];
  int r0 = blockIdx.x*32;
  int tid = threadIdx.x;
  int w = tid>>6, l = tid&63, lr = l&15, lg = l>>4;
  for (int idx=tid; idx<32*128; idx+=512){
    int pp=idx>>7, kk=idx&127;
    float vm = m2[(size_t)(r0+pp)*DD+kk];
    float vg = gout[(size_t)(r0+pp)*DD+kk];
    ushort_t hm=f2bf(vm); MsH[pp][kk]=hm; MsL[pp][kk]=f2bf(vm-bf2f(hm));
    ushort_t hg=f2bf(vg); GsH[pp][kk]=hg; GsL[pp][kk]=f2bf(vg-bf2f(hg));
  }
  __syncthreads();
  int c = w*16 + lr;
  f4_t xz0=(f4_t)(0.f), xr0=(f4_t)(0.f), xh0=(f4_t)(0.f);
  f4_t xz1=(f4_t)(0.f), xr1=(f4_t)(0.f), xh1=(f4_t)(0.f);
  f4_t hz0=(f4_t)(0.f), hr0=(f4_t)(0.f), hh0=(f4_t)(0.f);
  f4_t hz1=(f4_t)(0.f), hr1=(f4_t)(0.f), hh1=(f4_t)(0.f);
  #pragma unroll
  for (int kt=0; kt<4; kt++){
    int kof = kt*32 + lg*8;
    const bf8_t MA0h = *(const bf8_t*)&MsH[lr][kof];
    const bf8_t MA0l = *(const bf8_t*)&MsL[lr][kof];
    const bf8_t MA1h = *(const bf8_t*)&MsH[16+lr][kof];
    const bf8_t MA1l = *(const bf8_t*)&MsL[16+lr][kof];
    const bf8_t GA0h = *(const bf8_t*)&GsH[lr][kof];
    const bf8_t GA0l = *(const bf8_t*)&GsL[lr][kof];
    const bf8_t GA1h = *(const bf8_t*)&GsH[16+lr][kof];
    const bf8_t GA1l = *(const bf8_t*)&GsL[16+lr][kof];
    const bf8_t Wzh = *(const bf8_t*)(WnH + ((size_t)(      c))*128 + kof);
    const bf8_t Wzl = *(const bf8_t*)(WnL + ((size_t)(      c))*128 + kof);
    const bf8_t Wrh = *(const bf8_t*)(WnH + ((size_t)(128 + c))*128 + kof);
    const bf8_t Wrl = *(const bf8_t*)(WnL + ((size_t)(128 + c))*128 + kof);
    const bf8_t Whh = *(const bf8_t*)(WnH + ((size_t)(256 + c))*128 + kof);
    const bf8_t Whl = *(const bf8_t*)(WnL + ((size_t)(256 + c))*128 + kof);
    const bf8_t Uzh = *(const bf8_t*)(UnH + ((size_t)(      c))*128 + kof);
    const bf8_t Uzl = *(const bf8_t*)(UnL + ((size_t)(      c))*128 + kof);
    const bf8_t Urh = *(const bf8_t*)(UnH + ((size_t)(128 + c))*128 + kof);
    const bf8_t Url = *(const bf8_t*)(UnL + ((size_t)(128 + c))*128 + kof);
    const bf8_t Uhh = *(const bf8_t*)(UnH + ((size_t)(256 + c))*128 + kof);
    const bf8_t Uhl = *(const bf8_t*)(UnL + ((size_t)(256 + c))*128 + kof);
    xz0 = __builtin_amdgcn_mfma_f32_16x16x32_bf16(MA0h,Wzh,xz0,0,0,0);
    xz0 = __builtin_amdgcn_mfma_f32_16x16x32_bf16(MA0l,Wzh,xz0,0,0,0);
    xz0 = __builtin_amdgcn_mfma_f32_16x16x32_bf16(MA0h,Wzl,xz0,0,0,0);
    xz1 = __builtin_amdgcn_mfma_f32_16x16x32_bf16(MA1h,Wzh,xz1,0,0,0);
    xz1 = __builtin_amdgcn_mfma_f32_16x16x32_bf16(MA1l,Wzh,xz1,0,0,0);
    xz1 = __builtin_amdgcn_mfma_f32_16x16x32_bf16(MA1h,Wzl,xz1,0,0,0);
    xr0 = __builtin_amdgcn_mfma_f32_16x16x32_bf16(MA0h,Wrh,xr0,0,0,0);
    xr0 = __builtin_amdgcn_mfma_f32_16x16x32_bf16(MA0l,Wrh,xr0,0,0,0);
    xr0 = __builtin_amdgcn_mfma_f32_16x16x32_bf16(MA0h,Wrl,xr0,0,0,0);
    xr1 = __builtin_amdgcn_mfma_f32_16x16x32_bf16(MA1h,Wrh,xr1,0,0,0);
    xr1 = __builtin_amdgcn_mfma_f32_16x16x32_bf16(MA1l,Wrh,xr1,0,0,0);
    xr1 = __builtin_amdgcn_mfma_f32_16x16x32_bf16(MA1h,Wrl,xr1,0,0,0);
    xh0 = __builtin_amdgcn_mfma_f32_16x16x32_bf16(MA0h,Whh,xh0,0,0,0);
    xh0 = __builtin_amdgcn_mfma_f32_16x16x32_bf16(MA0l,Whh,xh0,0,0,0);
    xh0 = __builtin_amdgcn_mfma_f32_16x16x32_bf16(MA0h,Whl,xh0,0,0,0);
    xh1 = __builtin_amdgcn_mfma_f32_16x16x32_bf16(MA1h,Whh,xh1,0,0,0);
    xh1 = __builtin_amdgcn_mfma_f32_16x16x32_bf16(MA1l,Whh,xh1,0,0,0);
    xh1 = __builtin_amdgcn_mfma_f32_16x16x32_bf16(MA1h,Whl,xh1,0,0,0);
    hz0 = __builtin_amdgcn_mfma_f32_16x16x32_bf16(GA0h,Uzh,hz0,0,0,0);
    hz0 = __builtin_amdgcn_mfma_f32_16x16x32_bf16(GA0l,Uzh,hz0,0,0,0);
    hz0 = __builtin_amdgcn_mfma_f32_16x16x32_bf16(GA0h,Uzl,hz0,0,0,0);
    hz1 = __builtin_amdgcn_mfma_f32_16x16x32_bf16(GA1h,Uzh,hz1,0,0,0);
    hz1 = __builtin_amdgcn_mfma_f32_16x16x32_bf16(GA1l,Uzh,hz1,0,0,0);
    hz1 = __builtin_amdgcn_mfma_f32_16x16x32_bf16(GA1h,Uzl,hz1,0,0,0);
    hr0 = __builtin_amdgcn_mfma_f32_16x16x32_bf16(GA0h,Urh,hr0,0,0,0);
    hr0 = __builtin_amdgcn_mfma_f32_16x16x32_bf16(GA0l,Urh,hr0,0,0,0);
    hr0 = __builtin_amdgcn_mfma_f32_16x16x32_bf16(GA0h,Url,hr0,0,0,0);
    hr1 = __builtin_amdgcn_mfma_f32_16x16x32_bf16(GA1h,Urh,hr1,0,0,0);
    hr1 = __builtin_amdgcn_mfma_f32_16x16x32_bf16(GA1l,Urh,hr1,0,0,0);
    hr1 = __builtin_amdgcn_mfma_f32_16x16x32_bf16(GA1h,Url,hr1,0,0,0);
    hh0 = __builtin_amdgcn_mfma_f32_16x16x32_bf16(GA0h,Uhh,hh0,0,0,0);
    hh0 = __builtin_amdgcn_mfma_f32_16x16x32_bf16(GA0l,Uhh,hh0,0,0,0);
    hh0 = __builtin_amdgcn_mfma_f32_16x16x32_bf16(GA0h,Uhl,hh0,0,0,0);
    hh1 = __builtin_amdgcn_mfma_f32_16x16x32_bf16(GA1h,Uhh,hh1,0,0,0);
    hh1 = __builtin_amdgcn_mfma_f32_16x16x32_bf16(GA1l,Uhh,hh1,0,0,0);
    hh1 = __builtin_amdgcn_mfma_f32_16x16x32_bf16(GA1h,Uhl,hh1,0,0,0);
  }
  float bz = bn[c] + bn[G3+c] + gbUn[c];
  float br = bn[128+c] + bn[G3+128+c] + gbUn[128+c];
  float bxh = bn[256+c], bhh = bn[G3+256+c] + gbUn[256+c];
  float gbc = gb[c];
  #pragma unroll
  for (int q=0;q<4;q++){
    {
      int n = lg*4+q;
      float hval = bf2f(GsH[n][c]) + bf2f(GsL[n][c]) + gbc;
      float z = sigf(xz0[q] + hz0[q] + bz);
      float r = sigf(xr0[q] + hr0[q] + br);
      float hc = tanh_fast(xh0[q] + bxh + r*(hh0[q] + bhh));
      ns[(size_t)(r0+n)*DD + c] = z*hval + (1.f-z)*hc;
    }
    {
      int n = 16+lg*4+q;
      float hval = bf2f(GsH[n][c]) + bf2f(GsL[n][c]) + gbc;
      float z = sigf(xz1[q] + hz1[q] + bz);
      float r = sigf(xr1[q] + hr1[q] + br);
      float hc = tanh_fast(xh1[q] + bxh + r*(hh1[q] + bhh));
      ns[(size_t)(r0+n)*DD + c] = z*hval + (1.f-z)*hc;
    }
  }
}

/* ---------------- MFMA readout ---------------- */
__global__ __launch_bounds__(512) void k_read2(
    const float* __restrict__ ps,
    const ushort_t* __restrict__ r1h, const ushort_t* __restrict__ r1l,
    const ushort_t* __restrict__ r2h, const ushort_t* __restrict__ r2l,
    const float* __restrict__ rb1, const float* __restrict__ rb2,
    const float* __restrict__ rW3, const float* __restrict__ rb3,
    float* __restrict__ out)
{
  __shared__ __align__(16) ushort_t XsH[32][136], XsL[32][136];
  __shared__ __align__(16) char buf[32*264*2*2];
  ushort_t (*H1H)[264] = (ushort_t(*)[264])buf;
  ushort_t (*H1L)[264] = (ushort_t(*)[264])(buf + 32*264*2);
  float (*H2)[257] = (float(*)[257])buf;
  int pb = blockIdx.x*32, tid = threadIdx.x;
  int w = tid>>6, l = tid&63, lr = l&15, lg = l>>4;
  for (int idx=tid; idx<32*128; idx+=512){
    int pp=idx>>7, kk=idx&127;
    float v = ps[(size_t)(pb+pp)*DD+kk];
    ushort_t hi=f2bf(v); XsH[pp][kk]=hi; XsL[pp][kk]=f2bf(v-bf2f(hi));
  }
  __syncthreads();
  int col0 = w*32 + lr, col1 = col0 + 16;
  f4_t a00=(f4_t)(0.f), a01=(f4_t)(0.f), a10=(f4_t)(0.f), a11=(f4_t)(0.f);
  #pragma unroll
  for (int kt=0; kt<4; kt++){
    int kof = kt*32 + lg*8;
    const bf8_t Ah0 = *(const bf8_t*)&XsH[lr][kof];
    const bf8_t Al0 = *(const bf8_t*)&XsL[lr][kof];
    const bf8_t Ah1 = *(const bf8_t*)&XsH[16+lr][kof];
    const bf8_t Al1 = *(const bf8_t*)&XsL[16+lr][kof];
    const bf8_t B0h = *(const bf8_t*)(r1h + (size_t)col0*128 + kof);
    const bf8_t B0l = *(const bf8_t*)(r1l + (size_t)col0*128 + kof);
    const bf8_t B1h = *(const bf8_t*)(r1h + (size_t)col1*128 + kof);
    const bf8_t B1l = *(const bf8_t*)(r1l + (size_t)col1*128 + kof);
    a00 = __builtin_amdgcn_mfma_f32_16x16x32_bf16(Ah0,B0h,a00,0,0,0);
    a00 = __builtin_amdgcn_mfma_f32_16x16x32_bf16(Al0,B0h,a00,0,0,0);
    a00 = __builtin_amdgcn_mfma_f32_16x16x32_bf16(Ah0,B0l,a00,0,0,0);
    a01 = __builtin_amdgcn_mfma_f32_16x16x32_bf16(Ah0,B1h,a01,0,0,0);
    a01 = __builtin_amdgcn_mfma_f32_16x16x32_bf16(Al0,B1h,a01,0,0,0);
    a01 = __builtin_amdgcn_mfma_f32_16x16x32_bf16(Ah0,B1l,a01,0,0,0);
    a10 = __builtin_amdgcn_mfma_f32_16x16x32_bf16(Ah1,B0h,a10,0,0,0);
    a10 = __builtin_amdgcn_mfma_f32_16x16x32_bf16(Al1,B0h,a10,0,0,0);
    a10 = __builtin_amdgcn_mfma_f32_16x16x32_bf16(Ah1,B0l,a10,0,0,0);
    a11 = __builtin_amdgcn_mfma_f32_16x16x32_bf16(Ah1,B1h,a11,0,0,0);
    a11 = __builtin_amdgcn_mfma_f32_16x16x32_bf16(Al1,B1h,a11,0,0,0);
    a11 = __builtin_amdgcn_mfma_f32_16x16x32_bf16(Ah1,B1l,a11,0,0,0);
  }
  float rb1c0 = rb1[col0], rb1c1 = rb1[col1];
  #pragma unroll
  for (int q=0;q<4;q++){
    int row0 = lg*4+q, row1 = 16+lg*4+q;
    float v00 = a00[q]+rb1c0, v01 = a01[q]+rb1c1, v10 = a10[q]+rb1c0, v11 = a11[q]+rb1c1;
    v00 = 1.0507009873554805f * (v00>0.f ? v00 : 1.6732632423543772f*(__expf(v00)-1.f));
    v01 = 1.0507009873554805f * (v01>0.f ? v01 : 1.6732632423543772f*(__expf(v01)-1.f));
    v10 = 1.0507009873554805f * (v10>0.f ? v10 : 1.6732632423543772f*(__expf(v10)-1.f));
    v11 = 1.0507009873554805f * (v11>0.f ? v11 : 1.6732632423543772f*(__expf(v11)-1.f));
    ushort_t h;
    h=f2bf(v00); H1H[row0][col0]=h; H1L[row0][col0]=f2bf(v00-bf2f(h));
    h=f2bf(v01); H1H[row0][col1]=h; H1L[row0][col1]=f2bf(v01-bf2f(h));
    h=f2bf(v10); H1H[row1][col0]=h; H1L[row1][col0]=f2bf(v10-bf2f(h));
    h=f2bf(v11); H1H[row1][col1]=h; H1L[row1][col1]=f2bf(v11-bf2f(h));
  }
  __syncthreads();
  f4_t c00=(f4_t)(0.f), c01=(f4_t)(0.f), c10=(f4_t)(0.f), c11=(f4_t)(0.f);
  #pragma unroll
  for (int kt=0; kt<8; kt++){
    int kof = kt*32 + lg*8;
    const bf8_t Ah0 = *(const bf8_t*)&H1H[lr][kof];
    const bf8_t Al0 = *(const bf8_t*)&H1L[lr][kof];
    const bf8_t Ah1 = *(const bf8_t*)&H1H[16+lr][kof];
    const bf8_t Al1 = *(const bf8_t*)&H1L[16+lr][kof];
    const bf8_t B0h = *(const bf8_t*)(r2h + (size_t)col0*256 + kof);
    const bf8_t B0l = *(const bf8_t*)(r2l + (size_t)col0*256 + kof);
    const bf8_t B1h = *(const bf8_t*)(r2h + (size_t)col1*256 + kof);
    const bf8_t B1l = *(const bf8_t*)(r2l + (size_t)col1*256 + kof);
    c00 = __builtin_amdgcn_mfma_f32_16x16x32_bf16(Ah0,B0h,c00,0,0,0);
    c00 = __builtin_amdgcn_mfma_f32_16x16x32_bf16(Al0,B0h,c00,0,0,0);
    c00 = __builtin_amdgcn_mfma_f32_16x16x32_bf16(Ah0,B0l,c00,0,0,0);
    c01 = __builtin_amdgcn_mfma_f32_16x16x32_bf16(Ah0,B1h,c01,0,0,0);
    c01 = __builtin_amdgcn_mfma_f32_16x16x32_bf16(Al0,B1h,c01,0,0,0);
    c01 = __builtin_amdgcn_mfma_f32_16x16x32_bf16(Ah0,B1l,c01,0,0,0);
    c10 = __builtin_amdgcn_mfma_f32_16x16x32_bf16(Ah1,B0h,c10,0,0,0);
    c10 = __builtin_amdgcn_mfma_f32_16x16x32_bf16(Al1,B0h,c10,0,0,0);
    c10 = __builtin_amdgcn_mfma_f32_16x16x32_bf16(Ah1,B0l,c10,0,0,0);
    c11 = __builtin_amdgcn_mfma_f32_16x16x32_bf16(Ah1,B1h,c11,0,0,0);
    c11 = __builtin_amdgcn_mfma_f32_16x16x32_bf16(Al1,B1h,c11,0,0,0);
    c11 = __builtin_amdgcn_mfma_f32_16x16x32_bf16(Ah1,B1l,c11,0,0,0);
  }
  __syncthreads();
  float rb2c0 = rb2[col0], rb2c1 = rb2[col1];
  #pragma unroll
  for (int q=0;q<4;q++){
    int row0 = lg*4+q, row1 = 16+lg*4+q;
    H2[row0][col0] = fmaxf(c00[q]+rb2c0, 0.f);
    H2[row0][col1] = fmaxf(c01[q]+rb2c1, 0.f);
    H2[row1][col0] = fmaxf(c10[q]+rb2c0, 0.f);
    H2[row1][col1] = fmaxf(c11[q]+rb2c1, 0.f);
  }
  __syncthreads();
  int r = tid>>4, j0 = tid&15;
  float s = 0.f;
  for (int j=j0; j<256; j+=16) s += H2[r][j]*rW3[j];
  for (int o=8;o>0;o>>=1) s += __shfl_xor(s,o);
  if (j0==0) out[pb+r] = s + rb3[0];
}

/* ---------------- host ---------------- */
extern "C" void kernel_launch(void* const* d_in, const int* in_sizes, int n_in,
                              void* d_out, int out_size, void* d_ws, size_t ws_size,
                              hipStream_t stream)
{
  const float* ToS   = (const float*)d_in[0];
  const float* bw    = (const float*)d_in[1];
  const float* qpol  = (const float*)d_in[2];
  const float* w1    = (const float*)d_in[3];
  const float* w2    = (const float*)d_in[4];
  const float* w3    = (const float*)d_in[5];
  const float* qs    = (const float*)d_in[6];
  const float* lc    = (const float*)d_in[7];
  const float* gat_W = (const float*)d_in[8];
  const float* gat_as= (const float*)d_in[9];
  const float* gat_an= (const float*)d_in[10];
  const float* gat_b = (const float*)d_in[11];
  const float* Wp    = (const float*)d_in[12];
  const float* Up    = (const float*)d_in[13];
  const float* bp    = (const float*)d_in[14];
  const float* Wb    = (const float*)d_in[15];
  const float* Ub    = (const float*)d_in[16];
  const float* bb    = (const float*)d_in[17];
  const float* Wn    = (const float*)d_in[18];
  const float* Un    = (const float*)d_in[19];
  const float* bn    = (const float*)d_in[20];
  const float* rW1   = (const float*)d_in[21];
  const float* rb1   = (const float*)d_in[22];
  const float* rW2   = (const float*)d_in[23];
  const float* rb2   = (const float*)d_in[24];
  const float* rW3   = (const float*)d_in[25];
  const float* rb3   = (const float*)d_in[26];
  const int* paths   = (const int*)d_in[27];
  const int* seqs    = (const int*)d_in[28];
  const int* nodes   = (const int*)d_in[29];
  const int* adj_idx = (const int*)d_in[30];
  int E = in_sizes[27];

  char* w0 = (char*)d_ws;
  char* w = w0;
  auto alloc = [&](size_t nbytes)->void*{ void* r=(void*)w; w += (nbytes + 255) & ~(size_t)255; return r; };
  float* ns     = (float*)alloc((size_t)NN*DD*4);
  float* gout   = (float*)alloc((size_t)NN*DD*4);
  float* psA    = (float*)alloc((size_t)NP*DD*4);
  float* psB    = (float*)alloc((size_t)NP*DD*4);
  ushort_t* xpTh= (ushort_t*)alloc((size_t)NHD*NN*2);
  ushort_t* xpTl= (ushort_t*)alloc((size_t)NHD*NN*2);
  float* es     = (float*)alloc((size_t)NN*NH*4);
  float* en     = (float*)alloc((size_t)NN*NH*4);
  unsigned int* adjb = (unsigned int*)alloc((size_t)NN*16*4);
  float* xgp    = (float*)alloc((size_t)NN*G3*4);
  float* xgb    = (float*)alloc((size_t)NN*G3*4);
  float* m2     = (float*)alloc((size_t)NN*DD*4);
  float* bxgF   = (float*)alloc((size_t)G3*4);
  float* bxgB   = (float*)alloc((size_t)G3*4);
  float* gbUn   = (float*)alloc((size_t)G3*4);
  ushort_t* Uthp = (ushort_t*)alloc((size_t)G3*DD*2);
  ushort_t* Utlp = (ushort_t*)alloc((size_t)G3*DD*2);
  ushort_t* Uthb = (ushort_t*)alloc((size_t)G3*DD*2);
  ushort_t* Utlb = (ushort_t*)alloc((size_t)G3*DD*2);
  ushort_t* Wpth = (ushort_t*)alloc((size_t)G3*DD*2);
  ushort_t* Wptl = (ushort_t*)alloc((size_t)G3*DD*2);
  ushort_t* Wbth = (ushort_t*)alloc((size_t)G3*DD*2);
  ushort_t* Wbtl = (ushort_t*)alloc((size_t)G3*DD*2);
  ushort_t* WnTh = (ushort_t*)alloc((size_t)G3*DD*2);
  ushort_t* WnTl = (ushort_t*)alloc((size_t)G3*DD*2);
  ushort_t* UnTh = (ushort_t*)alloc((size_t)G3*DD*2);
  ushort_t* UnTl = (ushort_t*)alloc((size_t)G3*DD*2);
  ushort_t* r1h = (ushort_t*)alloc((size_t)256*128*2);
  ushort_t* r1l = (ushort_t*)alloc((size_t)256*128*2);
  ushort_t* r2h = (ushort_t*)alloc((size_t)256*256*2);
  ushort_t* r2l = (ushort_t*)alloc((size_t)256*256*2);
  ushort_t* gwh = (ushort_t*)alloc((size_t)NHD*DD*2);
  ushort_t* gwl = (ushort_t*)alloc((size_t)NHD*DD*2);
  int* start    = (int*)alloc((size_t)NP*4);
  int* lens     = (int*)alloc((size_t)NP*4);
  int* perm     = (int*)alloc((size_t)NP*4);
  int* lcnt     = (int*)alloc(16*4);
  int* loff     = (int*)alloc(16*4);
  int* lcur     = (int*)alloc(16*4);
  (void)n_in; (void)out_size; (void)ws_size;

  hipMemsetAsync(adjb, 0, (size_t)NN*16*4, stream);
  hipMemsetAsync(lcnt, 0, 16*4, stream);
  k_init_ns<<<NN,DD,0,stream>>>(ns, qpol, w1, w2, w3, qs);
  k_init_ps<<<(NP*DD+255)/256,256,0,stream>>>(psA, bw, ToS);
  k_adj<<<16,256,0,stream>>>(adjb, adj_idx, lc);
  k_meta<<<(E+255)/256,256,0,stream>>>(paths, seqs, start, lens, E);
  k_lcount<<<(NP+255)/256,256,0,stream>>>(lens, lcnt);
  k_lscan<<<1,64,0,stream>>>(lcnt, loff, lcur);
  k_lfill<<<(NP+255)/256,256,0,stream>>>(lens, lcur, perm);
  k_wsplit6<<<(6*G3*DD+255)/256,256,0,stream>>>(Up, Ub, Wp, Wb, Wn, Un,
      Uthp,Utlp, Uthb,Utlb, Wpth,Wptl, Wbth,Wbtl, WnTh,WnTl, UnTh,UnTl);
  k_wsplit<<<(256*128+255)/256,256,0,stream>>>(rW1, r1h, r1l, 7, 256, 256*128);
  k_wsplit<<<(256*256+255)/256,256,0,stream>>>(rW2, r2h, r2l, 8, 256, 256*256);
  k_wsplit<<<(NHD*DD+255)/256,256,0,stream>>>(gat_W, gwh, gwl, 7, NHD, NHD*DD);
  k_gbw<<<3,G3,0,stream>>>(gat_b, Wp, Wb, Un, bp, bb, bxgF, bxgB, gbUn);

  float* ps_cur = psA; float* ps_nxt = psB;
  for (int t=0;t<3;t++){
    k_xp2<<<dim3(NN/32, NHD/256),512,0,stream>>>(ns, gwh, gwl, gat_as, gat_an, xpTh, xpTl, es, en, gout);
    k_attn2<<<dim3(NH, NN/32),512,0,stream>>>(xpTh, xpTl, es, en, adjb, gout);
    k_xg3<<<dim3(NN/32,6),512,0,stream>>>(gout, Wpth, Wptl, Wbth, Wbtl, bxgF, bxgB, xgp, xgb, m2);
    k_gru2<<<2*(NP/32),512,0,stream>>>(ps_cur, ps_nxt, xgp, xgb, Uthp, Utlp, Uthb, Utlb,
                                       bp+G3, bb+G3, start, lens, nodes, perm, m2);
    k_ngru3<<<NN/32,512,0,stream>>>(m2, gout, WnTh, WnTl, UnTh, UnTl, bn, gat_b, gbUn, ns);
    float* tmp = ps_cur; ps_cur = ps_nxt; ps_nxt = tmp;
  }
  k_read2<<<NP/32,512,0,stream>>>(ps_cur, r1h, r1l, r2h, r2l, rb1, rb2, rW3, rb3, (float*)d_out);
}